// Round 8
// baseline (342.074 us; speedup 1.0000x reference)
//
#include <hip/hip_runtime.h>
#include <math.h>

typedef unsigned short u16;
typedef unsigned int u32;
typedef __attribute__((ext_vector_type(8))) short bf8;   // 8 bf16 = 4 VGPR
typedef __attribute__((ext_vector_type(4))) float f4;    // 4 f32 acc

__device__ __forceinline__ u16 bfhi(float x) {
    u32 u = __float_as_uint(x);
    u32 r = u + 0x7FFFu + ((u >> 16) & 1u);   // RNE
    return (u16)(r >> 16);
}
__device__ __forceinline__ float bf2f(u16 h) { return __uint_as_float(((u32)h) << 16); }

// ---------------- degree / norm ----------------

__global__ void deg_kernel(const int* __restrict__ col, int* __restrict__ deg, int E) {
    int e = blockIdx.x * blockDim.x + threadIdx.x;
    if (e < E) atomicAdd(&deg[col[e]], 1);
}

__global__ void dinv_kernel(const int* __restrict__ deg, float* __restrict__ dinv, int n) {
    int i = blockIdx.x * blockDim.x + threadIdx.x;
    if (i < n) dinv[i] = 1.0f / sqrtf((float)(deg[i] + 1));  // +1 self loop
}

// ---------------- 3-phase scan: deg -> rowptr/cursor ----------------
__global__ void scan_phase1(const int* __restrict__ deg, int* __restrict__ bsum, int n) {
    __shared__ int red[256];
    int tid = threadIdx.x;
    int base = blockIdx.x * 1024 + tid * 4;
    int s = 0;
    if (base + 3 < n) { int4 v = *(const int4*)&deg[base]; s = v.x + v.y + v.z + v.w; }
    else { for (int i = 0; i < 4; ++i) if (base + i < n) s += deg[base + i]; }
    red[tid] = s; __syncthreads();
    for (int off = 128; off > 0; off >>= 1) { if (tid < off) red[tid] += red[tid + off]; __syncthreads(); }
    if (tid == 0) bsum[blockIdx.x] = red[0];
}

__global__ void scan_phase2(const int* __restrict__ bsum, int* __restrict__ bpre,
                            int nb, int* __restrict__ rowptr, int n, int E) {
    int tid = threadIdx.x;  // 64 threads
    int sv = (tid < nb) ? bsum[tid] : 0;
    int v = sv;
    for (int off = 1; off < 64; off <<= 1) {
        int w = __shfl_up(v, off);
        if (tid >= off) v += w;
    }
    if (tid < nb) bpre[tid] = v - sv;   // exclusive
    if (tid == 0) rowptr[n] = E;
}

__global__ void scan_phase3(const int* __restrict__ deg, const int* __restrict__ bpre,
                            int* __restrict__ rowptr, int* __restrict__ cursor, int n) {
    __shared__ int tsum[256];
    int tid = threadIdx.x;
    int base = blockIdx.x * 1024 + tid * 4;
    int d[4] = {0, 0, 0, 0};
    if (base + 3 < n) { int4 v = *(const int4*)&deg[base]; d[0] = v.x; d[1] = v.y; d[2] = v.z; d[3] = v.w; }
    else { for (int i = 0; i < 4; ++i) if (base + i < n) d[i] = deg[base + i]; }
    int s = d[0] + d[1] + d[2] + d[3];
    tsum[tid] = s; __syncthreads();
    for (int off = 1; off < 256; off <<= 1) {
        int v = tsum[tid];
        int w = (tid >= off) ? tsum[tid - off] : 0;
        __syncthreads();
        tsum[tid] = v + w;
        __syncthreads();
    }
    int pre = bpre[blockIdx.x] + tsum[tid] - s;
    for (int i = 0; i < 4; ++i) {
        int idx = base + i;
        if (idx < n) { rowptr[idx] = pre; cursor[idx] = pre; pre += d[i]; }
    }
}

__global__ void fill_kernel(const int* __restrict__ row, const int* __restrict__ col,
                            int* __restrict__ cursor, int* __restrict__ csrc, int E) {
    int e = blockIdx.x * blockDim.x + threadIdx.x;
    if (e < E) {
        int c = col[e];
        int slot = atomicAdd(&cursor[c], 1);
        csrc[slot] = row[e];
    }
}

// ---------------- CSR gather aggregation + finalize ----------------
template<int F, bool OV>
__global__ void agg_finalize(const int* __restrict__ rowptr, const int* __restrict__ csrc,
                             const float* __restrict__ hs, const float* __restrict__ dinv,
                             const float* __restrict__ b, float* __restrict__ out,
                             int n, int ostride, int col0) {
    constexpr int L = F / 4;                 // lanes per node
    int tid = blockIdx.x * blockDim.x + threadIdx.x;
    int node = tid / L, lane = tid % L;
    if (node >= n) return;
    int f0 = lane * 4;
    int beg = rowptr[node], end = rowptr[node + 1];
    float4 sum = make_float4(0.f, 0.f, 0.f, 0.f);
    for (int j = beg; j < end; ++j) {
        int s = csrc[j];                     // uniform across the L-lane group
        float4 v = *(const float4*)&hs[(size_t)s * F + f0];
        sum.x += v.x; sum.y += v.y; sum.z += v.z; sum.w += v.w;
    }
    float4 self = *(const float4*)&hs[(size_t)node * F + f0];
    float di = dinv[node];
    float r0 = fmaxf(di * (sum.x + self.x) + b[f0 + 0], 0.f);
    float r1 = fmaxf(di * (sum.y + self.y) + b[f0 + 1], 0.f);
    float r2 = fmaxf(di * (sum.z + self.z) + b[f0 + 2], 0.f);
    float r3 = fmaxf(di * (sum.w + self.w) + b[f0 + 3], 0.f);
    float* op = &out[(size_t)node * ostride + col0 + f0];
    if (OV) {
        *(float4*)op = make_float4(r0, r1, r2, r3);
    } else {
        op[0] = r0; op[1] = r1; op[2] = r2; op[3] = r3;
    }
}

// ---------------- GCN dense: out[r,c] = dinv[r] * sum_k x[r,k]*W[k,c] ----------------
template<int K, int OC>
__global__ __launch_bounds__(256) void gemm_gcn(
    const float* __restrict__ x, const float* __restrict__ W,
    const float* __restrict__ dinv, float* __restrict__ outp, int n) {
    constexpr int CG = OC / 8;        // col groups
    constexpr int RG = 256 / CG;      // row groups
    constexpr int ROWS = 64 / RG;     // rows per thread
    __shared__ float xL[64][K + 4];

    const int tid = threadIdx.x;
    const int cg = tid % CG, rg = tid / CG;
    const int c0 = cg * 8, r0 = rg * ROWS;
    const int row0 = blockIdx.x * 64;

#pragma unroll
    for (int i = 0; i < K / 16; ++i) {
        int e = tid + i * 256;
        int r = e / (K / 4), q = e % (K / 4);
        float4 v = make_float4(0.f, 0.f, 0.f, 0.f);
        if (row0 + r < n) v = *(const float4*)&x[(size_t)(row0 + r) * K + q * 4];
        *(float4*)&xL[r][q * 4] = v;
    }
    __syncthreads();

    float acc[ROWS][8];
#pragma unroll
    for (int r = 0; r < ROWS; ++r)
#pragma unroll
        for (int c = 0; c < 8; ++c) acc[r][c] = 0.f;

#pragma unroll 8
    for (int k = 0; k < K; ++k) {
        float4 w0 = *(const float4*)&W[(size_t)k * OC + c0];
        float4 w1 = *(const float4*)&W[(size_t)k * OC + c0 + 4];
        float wv[8] = {w0.x, w0.y, w0.z, w0.w, w1.x, w1.y, w1.z, w1.w};
        float xv[ROWS];
#pragma unroll
        for (int r = 0; r < ROWS; ++r) xv[r] = xL[r0 + r][k];
#pragma unroll
        for (int r = 0; r < ROWS; ++r)
#pragma unroll
            for (int c = 0; c < 8; ++c) acc[r][c] = fmaf(xv[r], wv[c], acc[r][c]);
    }

#pragma unroll
    for (int r = 0; r < ROWS; ++r) {
        int gr = row0 + r0 + r;
        if (gr >= n) continue;
        float di = dinv[gr];
        float* op = &outp[(size_t)gr * OC + c0];
        *(float4*)op = make_float4(acc[r][0] * di, acc[r][1] * di, acc[r][2] * di, acc[r][3] * di);
        *(float4*)(op + 4) = make_float4(acc[r][4] * di, acc[r][5] * di, acc[r][6] * di, acc[r][7] * di);
    }
}

// ---------------- weight pre-swizzle into MFMA B-fragment order ----------------
// B-frag for mfma_f32_16x16x32_bf16: lane l holds B[kt*32 + (l>>4)*8 + j][ct*16 + (l&15)], j=0..7
// tiles: 0..7 Wd1(32x128), 8..39 Wd2(128x128), 40..71 Wd3(128x128), 72 Wp(32x10 pad16)
__global__ void wswz_kernel(const float* __restrict__ Wd1, const float* __restrict__ Wd2,
                            const float* __restrict__ Wd3, const float* __restrict__ Wp,
                            u16* __restrict__ whi, u16* __restrict__ wlo) {
    int t = blockIdx.x, l = threadIdx.x;   // 73 blocks x 64 threads
    const float* W; int C, kt, ct;
    if (t < 8)       { W = Wd1; C = 128; kt = 0;           ct = t; }
    else if (t < 40) { W = Wd2; C = 128; kt = (t - 8) >> 3; ct = (t - 8) & 7; }
    else if (t < 72) { W = Wd3; C = 128; kt = (t - 40) >> 3; ct = (t - 40) & 7; }
    else             { W = Wp;  C = 10;  kt = 0;           ct = 0; }
    int kbase = kt * 32 + (l >> 4) * 8;
    int c = ct * 16 + (l & 15);
    size_t base = (size_t)t * 512 + (size_t)l * 8;
#pragma unroll
    for (int j = 0; j < 8; ++j) {
        float v = (c < C) ? W[(size_t)(kbase + j) * C + c] : 0.f;
        u16 h = bfhi(v);
        whi[base + j] = (u16)h;
        wlo[base + j] = bfhi(v - bf2f(h));
    }
}

// ---------------- MFMA fused decoder v2 ----------------
// 1 wave per block, 32 rows per wave (2 row-frags x 8 col-tiles).
// Batched B-fragment loads (bf8[8] arrays) for load-level parallelism.
// No __syncthreads: every LDS row is read/written by this wave only.
// LDS = 2 planes x [32][136] u16 = 17.4 KB.
__global__ __launch_bounds__(64, 2) void decoder_mfma(
    const float* __restrict__ obuf,
    const u16* __restrict__ whi, const u16* __restrict__ wlo,
    const float* __restrict__ bp, const float* __restrict__ bd1,
    const float* __restrict__ bd2, const float* __restrict__ bd3,
    float* __restrict__ out, int n) {
    __shared__ u16 hH[32][136], hL[32][136];   // emb planes (cols 0..31), then h1, then h2

    const int l = threadIdx.x;
    const int lr = l & 15, lg = l >> 4;
    const int row0 = blockIdx.x * 32;

    // ---- stage emb (32 x 32 f32) -> split planes, cols [0,32) ----
    {
        int r = l >> 1, q = (l & 1) * 16;
        bool ok = (row0 + r) < n;
        const float* src = &obuf[(size_t)(row0 + r) * 170 + q];
#pragma unroll
        for (int i = 0; i < 16; i += 2) {
            float2 v = ok ? *(const float2*)(src + i) : make_float2(0.f, 0.f);
            u16 h0 = bfhi(v.x), h1 = bfhi(v.y);
            u16 l0 = bfhi(v.x - bf2f(h0)), l1 = bfhi(v.y - bf2f(h1));
            *(u32*)&hH[r][q + i] = (u32)h0 | ((u32)h1 << 16);
            *(u32*)&hL[r][q + i] = (u32)l0 | ((u32)l1 << 16);
        }
    }
    // wave-local: program order + compiler waitcnts give LDS ordering; no barrier.

    f4 acc[2][8];
    // ---- stage 1: h1 = relu(emb @ Wd1 + bd1) (K=32) + head ----
    {
        bf8 aH0 = *(const bf8*)&hH[lr][lg * 8];
        bf8 aH1 = *(const bf8*)&hH[16 + lr][lg * 8];
        bf8 aL0 = *(const bf8*)&hL[lr][lg * 8];
        bf8 aL1 = *(const bf8*)&hL[16 + lr][lg * 8];
        bf8 bH[8], bL[8];
#pragma unroll
        for (int ct = 0; ct < 8; ++ct) {
            size_t tb = (size_t)ct * 512 + (size_t)l * 8;
            bH[ct] = *(const bf8*)(whi + tb);
            bL[ct] = *(const bf8*)(wlo + tb);
        }
#pragma unroll
        for (int ct = 0; ct < 8; ++ct) {
            f4 a0 = (f4){0.f, 0.f, 0.f, 0.f}, a1 = (f4){0.f, 0.f, 0.f, 0.f};
            a0 = __builtin_amdgcn_mfma_f32_16x16x32_bf16(aH0, bH[ct], a0, 0, 0, 0);
            a0 = __builtin_amdgcn_mfma_f32_16x16x32_bf16(aL0, bH[ct], a0, 0, 0, 0);
            a0 = __builtin_amdgcn_mfma_f32_16x16x32_bf16(aH0, bL[ct], a0, 0, 0, 0);
            a1 = __builtin_amdgcn_mfma_f32_16x16x32_bf16(aH1, bH[ct], a1, 0, 0, 0);
            a1 = __builtin_amdgcn_mfma_f32_16x16x32_bf16(aL1, bH[ct], a1, 0, 0, 0);
            a1 = __builtin_amdgcn_mfma_f32_16x16x32_bf16(aH1, bL[ct], a1, 0, 0, 0);
            acc[0][ct] = a0; acc[1][ct] = a1;
        }
        // head: tile 72 (Wp padded to 16 cols)
        {
            size_t tb = (size_t)72 * 512 + (size_t)l * 8;
            bf8 pH = *(const bf8*)(whi + tb);
            bf8 pL = *(const bf8*)(wlo + tb);
            f4 p0 = (f4){0.f, 0.f, 0.f, 0.f}, p1 = (f4){0.f, 0.f, 0.f, 0.f};
            p0 = __builtin_amdgcn_mfma_f32_16x16x32_bf16(aH0, pH, p0, 0, 0, 0);
            p0 = __builtin_amdgcn_mfma_f32_16x16x32_bf16(aL0, pH, p0, 0, 0, 0);
            p0 = __builtin_amdgcn_mfma_f32_16x16x32_bf16(aH0, pL, p0, 0, 0, 0);
            p1 = __builtin_amdgcn_mfma_f32_16x16x32_bf16(aH1, pH, p1, 0, 0, 0);
            p1 = __builtin_amdgcn_mfma_f32_16x16x32_bf16(aL1, pH, p1, 0, 0, 0);
            p1 = __builtin_amdgcn_mfma_f32_16x16x32_bf16(aH1, pL, p1, 0, 0, 0);
            if (lr < 10) {
                float bpv = bp[lr];
#pragma unroll
                for (int rg = 0; rg < 4; ++rg) {
                    int g0 = row0 + lg * 4 + rg;
                    int g1 = g0 + 16;
                    if (g0 < n) out[(size_t)g0 * 170 + 32 + lr] = p0[rg] + bpv;
                    if (g1 < n) out[(size_t)g1 * 170 + 32 + lr] = p1[rg] + bpv;
                }
            }
        }
        // write h1 planes (overwrites emb region; emb already consumed into regs)
#pragma unroll
        for (int ct = 0; ct < 8; ++ct) {
            float bv = bd1[ct * 16 + lr];
#pragma unroll
            for (int rf = 0; rf < 2; ++rf)
#pragma unroll
                for (int rg = 0; rg < 4; ++rg) {
                    float v = fmaxf(acc[rf][ct][rg] + bv, 0.f);
                    u16 vh = bfhi(v), vl = bfhi(v - bf2f(vh));
                    int rr = rf * 16 + lg * 4 + rg, cc = ct * 16 + lr;
                    hH[rr][cc] = vh; hL[rr][cc] = vl;
                }
        }
    }

    // ---- stage 2: h2 = relu(h1 @ Wd2 + bd2) (K=128) ----
    {
#pragma unroll
        for (int rf = 0; rf < 2; ++rf)
#pragma unroll
            for (int ct = 0; ct < 8; ++ct) acc[rf][ct] = (f4){0.f, 0.f, 0.f, 0.f};
#pragma unroll
        for (int kt = 0; kt < 4; ++kt) {
            bf8 aH0 = *(const bf8*)&hH[lr][kt * 32 + lg * 8];
            bf8 aH1 = *(const bf8*)&hH[16 + lr][kt * 32 + lg * 8];
            bf8 aL0 = *(const bf8*)&hL[lr][kt * 32 + lg * 8];
            bf8 aL1 = *(const bf8*)&hL[16 + lr][kt * 32 + lg * 8];
            bf8 bH[8], bL[8];
#pragma unroll
            for (int ct = 0; ct < 8; ++ct) {
                size_t tb = (size_t)(8 + kt * 8 + ct) * 512 + (size_t)l * 8;
                bH[ct] = *(const bf8*)(whi + tb);
                bL[ct] = *(const bf8*)(wlo + tb);
            }
#pragma unroll
            for (int ct = 0; ct < 8; ++ct) {
                acc[0][ct] = __builtin_amdgcn_mfma_f32_16x16x32_bf16(aH0, bH[ct], acc[0][ct], 0, 0, 0);
                acc[0][ct] = __builtin_amdgcn_mfma_f32_16x16x32_bf16(aL0, bH[ct], acc[0][ct], 0, 0, 0);
                acc[0][ct] = __builtin_amdgcn_mfma_f32_16x16x32_bf16(aH0, bL[ct], acc[0][ct], 0, 0, 0);
                acc[1][ct] = __builtin_amdgcn_mfma_f32_16x16x32_bf16(aH1, bH[ct], acc[1][ct], 0, 0, 0);
                acc[1][ct] = __builtin_amdgcn_mfma_f32_16x16x32_bf16(aL1, bH[ct], acc[1][ct], 0, 0, 0);
                acc[1][ct] = __builtin_amdgcn_mfma_f32_16x16x32_bf16(aH1, bL[ct], acc[1][ct], 0, 0, 0);
            }
        }
        // write h2 planes (all reads of h1 completed above in this wave)
#pragma unroll
        for (int ct = 0; ct < 8; ++ct) {
            float bv = bd2[ct * 16 + lr];
#pragma unroll
            for (int rf = 0; rf < 2; ++rf)
#pragma unroll
                for (int rg = 0; rg < 4; ++rg) {
                    float v = fmaxf(acc[rf][ct][rg] + bv, 0.f);
                    u16 vh = bfhi(v), vl = bfhi(v - bf2f(vh));
                    int rr = rf * 16 + lg * 4 + rg, cc = ct * 16 + lr;
                    hH[rr][cc] = vh; hL[rr][cc] = vl;
                }
        }
    }

    // ---- stage 3: dec = softplus(h2 @ Wd3 + bd3) -> out[:,42:170) ----
    {
#pragma unroll
        for (int rf = 0; rf < 2; ++rf)
#pragma unroll
            for (int ct = 0; ct < 8; ++ct) acc[rf][ct] = (f4){0.f, 0.f, 0.f, 0.f};
#pragma unroll
        for (int kt = 0; kt < 4; ++kt) {
            bf8 aH0 = *(const bf8*)&hH[lr][kt * 32 + lg * 8];
            bf8 aH1 = *(const bf8*)&hH[16 + lr][kt * 32 + lg * 8];
            bf8 aL0 = *(const bf8*)&hL[lr][kt * 32 + lg * 8];
            bf8 aL1 = *(const bf8*)&hL[16 + lr][kt * 32 + lg * 8];
            bf8 bH[8], bL[8];
#pragma unroll
            for (int ct = 0; ct < 8; ++ct) {
                size_t tb = (size_t)(40 + kt * 8 + ct) * 512 + (size_t)l * 8;
                bH[ct] = *(const bf8*)(whi + tb);
                bL[ct] = *(const bf8*)(wlo + tb);
            }
#pragma unroll
            for (int ct = 0; ct < 8; ++ct) {
                acc[0][ct] = __builtin_amdgcn_mfma_f32_16x16x32_bf16(aH0, bH[ct], acc[0][ct], 0, 0, 0);
                acc[0][ct] = __builtin_amdgcn_mfma_f32_16x16x32_bf16(aL0, bH[ct], acc[0][ct], 0, 0, 0);
                acc[0][ct] = __builtin_amdgcn_mfma_f32_16x16x32_bf16(aH0, bL[ct], acc[0][ct], 0, 0, 0);
                acc[1][ct] = __builtin_amdgcn_mfma_f32_16x16x32_bf16(aH1, bH[ct], acc[1][ct], 0, 0, 0);
                acc[1][ct] = __builtin_amdgcn_mfma_f32_16x16x32_bf16(aL1, bH[ct], acc[1][ct], 0, 0, 0);
                acc[1][ct] = __builtin_amdgcn_mfma_f32_16x16x32_bf16(aH1, bL[ct], acc[1][ct], 0, 0, 0);
            }
        }
#pragma unroll
        for (int ct = 0; ct < 8; ++ct) {
            float bv = bd3[ct * 16 + lr];
#pragma unroll
            for (int rf = 0; rf < 2; ++rf)
#pragma unroll
                for (int rg = 0; rg < 4; ++rg) {
                    int grow = row0 + rf * 16 + lg * 4 + rg;
                    if (grow < n) {
                        float v = acc[rf][ct][rg] + bv;
                        v = fmaxf(v, 0.f) + log1pf(expf(-fabsf(v)));
                        out[(size_t)grow * 170 + 42 + ct * 16 + lr] = v;
                    }
                }
        }
    }
}

// ---------------- launch ----------------

extern "C" void kernel_launch(void* const* d_in, const int* in_sizes, int n_in,
                              void* d_out, int out_size, void* d_ws, size_t ws_size,
                              hipStream_t stream) {
    const float* raw_x = (const float*)d_in[0];
    const int*   ei    = (const int*)d_in[1];
    const float* W1 = (const float*)d_in[2];  const float* b1 = (const float*)d_in[3];
    const float* W2 = (const float*)d_in[4];  const float* b2 = (const float*)d_in[5];
    const float* Wp = (const float*)d_in[6];  const float* bp = (const float*)d_in[7];
    const float* Wd1 = (const float*)d_in[8]; const float* bd1 = (const float*)d_in[9];
    const float* Wd2 = (const float*)d_in[10]; const float* bd2 = (const float*)d_in[11];
    const float* Wd3 = (const float*)d_in[12]; const float* bd3 = (const float*)d_in[13];

    const int n = in_sizes[0] / 128;   // 50000
    const int E = in_sizes[1] / 2;     // 800000
    const int* row = ei;        // source
    const int* col = ei + E;    // target

    float* out = (float*)d_out;

    // workspace layout
    char* ws = (char*)d_ws;
    int*   deg    = (int*)ws;                        ws += (size_t)n * 4;
    float* dinv   = (float*)ws;                      ws += (size_t)n * 4;
    int*   rowptr = (int*)ws;                        ws += (size_t)(n + 4) * 4;
    int*   cursor = (int*)ws;                        ws += (size_t)n * 4;
    int*   bsum   = (int*)ws;                        ws += 64 * 4;
    int*   bpre   = (int*)ws;                        ws += 64 * 4;
    int*   csrc   = (int*)ws;                        ws += (size_t)E * 4;
    float* hs1    = (float*)ws;                      // [n,64]
    float* x1     = hs1 + (size_t)n * 64;            // [n,64]
    float* hs2    = x1 + (size_t)n * 64;             // [n,32]
    u16*   wswHi  = (u16*)(hs2 + (size_t)n * 32);    // 73*512 u16
    u16*   wswLo  = wswHi + 73 * 512;

    const int BS = 256;
    auto blocks = [](long long work, int bs) { return (unsigned)((work + bs - 1) / bs); };
    const int nb = (n + 1023) / 1024;                // scan blocks (49)

    // ---- graph structure (CSR by target) + weight swizzle ----
    hipMemsetAsync(deg, 0, (size_t)n * 4, stream);
    wswz_kernel<<<73, 64, 0, stream>>>(Wd1, Wd2, Wd3, Wp, wswHi, wswLo);
    deg_kernel<<<blocks(E, BS), BS, 0, stream>>>(col, deg, E);
    dinv_kernel<<<blocks(n, BS), BS, 0, stream>>>(deg, dinv, n);
    scan_phase1<<<nb, 256, 0, stream>>>(deg, bsum, n);
    scan_phase2<<<1, 64, 0, stream>>>(bsum, bpre, nb, rowptr, n, E);
    scan_phase3<<<nb, 256, 0, stream>>>(deg, bpre, rowptr, cursor, n);
    fill_kernel<<<blocks(E, BS), BS, 0, stream>>>(row, col, cursor, csrc, E);

    // ---- GCN layer 1: raw_x[128] -> 64 ----
    gemm_gcn<128, 64><<<blocks(n, 64), 256, 0, stream>>>(raw_x, W1, dinv, hs1, n);
    agg_finalize<64, true><<<blocks((long long)n * 16, BS), BS, 0, stream>>>(
        rowptr, csrc, hs1, dinv, b1, x1, n, 64, 0);

    // ---- GCN layer 2: x1[64] -> 32 ----
    gemm_gcn<64, 32><<<blocks(n, 64), 256, 0, stream>>>(x1, W2, dinv, hs2, n);
    agg_finalize<32, false><<<blocks((long long)n * 8, BS), BS, 0, stream>>>(
        rowptr, csrc, hs2, dinv, b2, out, n, 170, 0);   // emb -> out[:,0:32)

    // ---- fused MFMA decoder: head + 3 dense layers ----
    decoder_mfma<<<blocks(n, 32), 64, 0, stream>>>(
        out, wswHi, wswLo, bp, bd1, bd2, bd3, out, n);
}

// Round 9
// 323.594 us; speedup vs baseline: 1.0571x; 1.0571x over previous
//
#include <hip/hip_runtime.h>
#include <math.h>

typedef unsigned short u16;
typedef unsigned int u32;
typedef __attribute__((ext_vector_type(8))) short bf8;   // 8 bf16 = 4 VGPR
typedef __attribute__((ext_vector_type(4))) float f4;    // 4 f32 acc

__device__ __forceinline__ u16 bfhi(float x) {
    u32 u = __float_as_uint(x);
    u32 r = u + 0x7FFFu + ((u >> 16) & 1u);   // RNE
    return (u16)(r >> 16);
}
__device__ __forceinline__ float bf2f(u16 h) { return __uint_as_float(((u32)h) << 16); }

// ---------------- degree / norm ----------------

__global__ void deg_kernel(const int* __restrict__ col, int* __restrict__ deg, int E) {
    int e = blockIdx.x * blockDim.x + threadIdx.x;
    if (e < E) atomicAdd(&deg[col[e]], 1);
}

__global__ void dinv_kernel(const int* __restrict__ deg, float* __restrict__ dinv, int n) {
    int i = blockIdx.x * blockDim.x + threadIdx.x;
    if (i < n) dinv[i] = 1.0f / sqrtf((float)(deg[i] + 1));  // +1 self loop
}

// ---------------- 3-phase scan: deg -> rowptr/cursor ----------------
__global__ void scan_phase1(const int* __restrict__ deg, int* __restrict__ bsum, int n) {
    __shared__ int red[256];
    int tid = threadIdx.x;
    int base = blockIdx.x * 1024 + tid * 4;
    int s = 0;
    if (base + 3 < n) { int4 v = *(const int4*)&deg[base]; s = v.x + v.y + v.z + v.w; }
    else { for (int i = 0; i < 4; ++i) if (base + i < n) s += deg[base + i]; }
    red[tid] = s; __syncthreads();
    for (int off = 128; off > 0; off >>= 1) { if (tid < off) red[tid] += red[tid + off]; __syncthreads(); }
    if (tid == 0) bsum[blockIdx.x] = red[0];
}

__global__ void scan_phase2(const int* __restrict__ bsum, int* __restrict__ bpre,
                            int nb, int* __restrict__ rowptr, int n, int E) {
    int tid = threadIdx.x;  // 64 threads
    int sv = (tid < nb) ? bsum[tid] : 0;
    int v = sv;
    for (int off = 1; off < 64; off <<= 1) {
        int w = __shfl_up(v, off);
        if (tid >= off) v += w;
    }
    if (tid < nb) bpre[tid] = v - sv;   // exclusive
    if (tid == 0) rowptr[n] = E;
}

__global__ void scan_phase3(const int* __restrict__ deg, const int* __restrict__ bpre,
                            int* __restrict__ rowptr, int* __restrict__ cursor, int n) {
    __shared__ int tsum[256];
    int tid = threadIdx.x;
    int base = blockIdx.x * 1024 + tid * 4;
    int d[4] = {0, 0, 0, 0};
    if (base + 3 < n) { int4 v = *(const int4*)&deg[base]; d[0] = v.x; d[1] = v.y; d[2] = v.z; d[3] = v.w; }
    else { for (int i = 0; i < 4; ++i) if (base + i < n) d[i] = deg[base + i]; }
    int s = d[0] + d[1] + d[2] + d[3];
    tsum[tid] = s; __syncthreads();
    for (int off = 1; off < 256; off <<= 1) {
        int v = tsum[tid];
        int w = (tid >= off) ? tsum[tid - off] : 0;
        __syncthreads();
        tsum[tid] = v + w;
        __syncthreads();
    }
    int pre = bpre[blockIdx.x] + tsum[tid] - s;
    for (int i = 0; i < 4; ++i) {
        int idx = base + i;
        if (idx < n) { rowptr[idx] = pre; cursor[idx] = pre; pre += d[i]; }
    }
}

__global__ void fill_kernel(const int* __restrict__ row, const int* __restrict__ col,
                            int* __restrict__ cursor, int* __restrict__ csrc, int E) {
    int e = blockIdx.x * blockDim.x + threadIdx.x;
    if (e < E) {
        int c = col[e];
        int slot = atomicAdd(&cursor[c], 1);
        csrc[slot] = row[e];
    }
}

// ---------------- CSR gather aggregation + finalize ----------------
template<int F, bool OV>
__global__ void agg_finalize(const int* __restrict__ rowptr, const int* __restrict__ csrc,
                             const float* __restrict__ hs, const float* __restrict__ dinv,
                             const float* __restrict__ b, float* __restrict__ out,
                             int n, int ostride, int col0) {
    constexpr int L = F / 4;                 // lanes per node
    int tid = blockIdx.x * blockDim.x + threadIdx.x;
    int node = tid / L, lane = tid % L;
    if (node >= n) return;
    int f0 = lane * 4;
    int beg = rowptr[node], end = rowptr[node + 1];
    float4 sum = make_float4(0.f, 0.f, 0.f, 0.f);
    for (int j = beg; j < end; ++j) {
        int s = csrc[j];                     // uniform across the L-lane group
        float4 v = *(const float4*)&hs[(size_t)s * F + f0];
        sum.x += v.x; sum.y += v.y; sum.z += v.z; sum.w += v.w;
    }
    float4 self = *(const float4*)&hs[(size_t)node * F + f0];
    float di = dinv[node];
    float r0 = fmaxf(di * (sum.x + self.x) + b[f0 + 0], 0.f);
    float r1 = fmaxf(di * (sum.y + self.y) + b[f0 + 1], 0.f);
    float r2 = fmaxf(di * (sum.z + self.z) + b[f0 + 2], 0.f);
    float r3 = fmaxf(di * (sum.w + self.w) + b[f0 + 3], 0.f);
    float* op = &out[(size_t)node * ostride + col0 + f0];
    if (OV) {
        *(float4*)op = make_float4(r0, r1, r2, r3);
    } else {
        op[0] = r0; op[1] = r1; op[2] = r2; op[3] = r3;
    }
}

// ---------------- GCN dense: out[r,c] = dinv[r] * sum_k x[r,k]*W[k,c] ----------------
template<int K, int OC>
__global__ __launch_bounds__(256) void gemm_gcn(
    const float* __restrict__ x, const float* __restrict__ W,
    const float* __restrict__ dinv, float* __restrict__ outp, int n) {
    constexpr int CG = OC / 8;        // col groups
    constexpr int RG = 256 / CG;      // row groups
    constexpr int ROWS = 64 / RG;     // rows per thread
    __shared__ float xL[64][K + 4];

    const int tid = threadIdx.x;
    const int cg = tid % CG, rg = tid / CG;
    const int c0 = cg * 8, r0 = rg * ROWS;
    const int row0 = blockIdx.x * 64;

#pragma unroll
    for (int i = 0; i < K / 16; ++i) {
        int e = tid + i * 256;
        int r = e / (K / 4), q = e % (K / 4);
        float4 v = make_float4(0.f, 0.f, 0.f, 0.f);
        if (row0 + r < n) v = *(const float4*)&x[(size_t)(row0 + r) * K + q * 4];
        *(float4*)&xL[r][q * 4] = v;
    }
    __syncthreads();

    float acc[ROWS][8];
#pragma unroll
    for (int r = 0; r < ROWS; ++r)
#pragma unroll
        for (int c = 0; c < 8; ++c) acc[r][c] = 0.f;

#pragma unroll 8
    for (int k = 0; k < K; ++k) {
        float4 w0 = *(const float4*)&W[(size_t)k * OC + c0];
        float4 w1 = *(const float4*)&W[(size_t)k * OC + c0 + 4];
        float wv[8] = {w0.x, w0.y, w0.z, w0.w, w1.x, w1.y, w1.z, w1.w};
        float xv[ROWS];
#pragma unroll
        for (int r = 0; r < ROWS; ++r) xv[r] = xL[r0 + r][k];
#pragma unroll
        for (int r = 0; r < ROWS; ++r)
#pragma unroll
            for (int c = 0; c < 8; ++c) acc[r][c] = fmaf(xv[r], wv[c], acc[r][c]);
    }

#pragma unroll
    for (int r = 0; r < ROWS; ++r) {
        int gr = row0 + r0 + r;
        if (gr >= n) continue;
        float di = dinv[gr];
        float* op = &outp[(size_t)gr * OC + c0];
        *(float4*)op = make_float4(acc[r][0] * di, acc[r][1] * di, acc[r][2] * di, acc[r][3] * di);
        *(float4*)(op + 4) = make_float4(acc[r][4] * di, acc[r][5] * di, acc[r][6] * di, acc[r][7] * di);
    }
}

// ---------------- weight pre-swizzle into MFMA B-fragment order ----------------
// B-frag for mfma_f32_16x16x32_bf16: lane l holds B[kt*32 + (l>>4)*8 + j][ct*16 + (l&15)], j=0..7
// tiles: 0..7 Wd1(32x128), 8..39 Wd2(128x128), 40..71 Wd3(128x128), 72 Wp(32x10 pad16)
__global__ void wswz_kernel(const float* __restrict__ Wd1, const float* __restrict__ Wd2,
                            const float* __restrict__ Wd3, const float* __restrict__ Wp,
                            u16* __restrict__ whi, u16* __restrict__ wlo) {
    int t = blockIdx.x, l = threadIdx.x;   // 73 blocks x 64 threads
    const float* W; int C, kt, ct;
    if (t < 8)       { W = Wd1; C = 128; kt = 0;           ct = t; }
    else if (t < 40) { W = Wd2; C = 128; kt = (t - 8) >> 3; ct = (t - 8) & 7; }
    else if (t < 72) { W = Wd3; C = 128; kt = (t - 40) >> 3; ct = (t - 40) & 7; }
    else             { W = Wp;  C = 10;  kt = 0;           ct = 0; }
    int kbase = kt * 32 + (l >> 4) * 8;
    int c = ct * 16 + (l & 15);
    size_t base = (size_t)t * 512 + (size_t)l * 8;
#pragma unroll
    for (int j = 0; j < 8; ++j) {
        float v = (c < C) ? W[(size_t)(kbase + j) * C + c] : 0.f;
        u16 h = bfhi(v);
        whi[base + j] = (u16)h;
        wlo[base + j] = bfhi(v - bf2f(h));
    }
}

// ---------------- MFMA fused decoder v3 ----------------
// 256 threads = 4 waves, 64 rows/block; wave w owns rows [w*16, w*16+16).
// Weights staged per-stage into LDS cooperatively (shared by all 4 waves);
// B-fragment reads become conflict-free ds_read_b128. h1/h2 wave-local in LDS.
// LDS = 34.8 KB (h planes) + 64 KB (weight stage) = ~99 KB -> 1 block/CU.
__global__ __launch_bounds__(256, 1) void decoder_mfma(
    const float* __restrict__ obuf,
    const u16* __restrict__ whi, const u16* __restrict__ wlo,
    const float* __restrict__ bp, const float* __restrict__ bd1,
    const float* __restrict__ bd2, const float* __restrict__ bd3,
    float* __restrict__ out, int n) {
    __shared__ __align__(16) u16 hH[64][136], hL[64][136];  // emb -> h1 -> h2 planes
    __shared__ __align__(16) u16 wbH[32][512], wbL[32][512]; // staged weight tiles

    const int tid = threadIdx.x;
    const int l = tid & 63, wv = tid >> 6;
    const int lr = l & 15, lg = l >> 4;
    const int row0 = blockIdx.x * 64;
    const int wrow = wv * 16;

    // ---- stage emb (64x32 f32 -> split planes). thread tid -> row tid>>2 (wave-local rows) ----
    {
        int r = tid >> 2, q = (tid & 3) * 8;
        bool ok = (row0 + r) < n;
        const float* src = &obuf[(size_t)(row0 + r) * 170 + q];
#pragma unroll
        for (int i = 0; i < 8; i += 2) {
            float2 v = ok ? *(const float2*)(src + i) : make_float2(0.f, 0.f);
            u16 h0 = bfhi(v.x), h1 = bfhi(v.y);
            u16 l0 = bfhi(v.x - bf2f(h0)), l1 = bfhi(v.y - bf2f(h1));
            *(u32*)&hH[r][q + i] = (u32)h0 | ((u32)h1 << 16);
            *(u32*)&hL[r][q + i] = (u32)l0 | ((u32)l1 << 16);
        }
    }

    // ---- stage Wd1 (tiles 0..7) + head (tile 72 -> slot 8) ----
    for (int i = tid; i < 9 * 64; i += 256) {
        int tl = i >> 6, e = i & 63;
        int st = (tl < 8) ? tl : 72;
        ((int4*)wbH)[(tl << 6) + e] = ((const int4*)whi)[(st << 6) + e];
        ((int4*)wbL)[(tl << 6) + e] = ((const int4*)wlo)[(st << 6) + e];
    }
    __syncthreads();

    f4 acc[8];
    // ---- stage 1: h1 = relu(emb @ Wd1 + bd1) (K=32) + head ----
    {
        bf8 aH = *(const bf8*)&hH[wrow + lr][lg * 8];
        bf8 aL = *(const bf8*)&hL[wrow + lr][lg * 8];
#pragma unroll
        for (int ct = 0; ct < 8; ++ct) {
            bf8 bH = *(const bf8*)&wbH[ct][l * 8];
            bf8 bL = *(const bf8*)&wbL[ct][l * 8];
            f4 a = (f4){0.f, 0.f, 0.f, 0.f};
            a = __builtin_amdgcn_mfma_f32_16x16x32_bf16(aH, bH, a, 0, 0, 0);
            a = __builtin_amdgcn_mfma_f32_16x16x32_bf16(aL, bH, a, 0, 0, 0);
            a = __builtin_amdgcn_mfma_f32_16x16x32_bf16(aH, bL, a, 0, 0, 0);
            acc[ct] = a;
        }
        {   // head (slot 8)
            bf8 pH = *(const bf8*)&wbH[8][l * 8];
            bf8 pL = *(const bf8*)&wbL[8][l * 8];
            f4 p = (f4){0.f, 0.f, 0.f, 0.f};
            p = __builtin_amdgcn_mfma_f32_16x16x32_bf16(aH, pH, p, 0, 0, 0);
            p = __builtin_amdgcn_mfma_f32_16x16x32_bf16(aL, pH, p, 0, 0, 0);
            p = __builtin_amdgcn_mfma_f32_16x16x32_bf16(aH, pL, p, 0, 0, 0);
            if (lr < 10) {
                float bpv = bp[lr];
#pragma unroll
                for (int rg = 0; rg < 4; ++rg) {
                    int g = row0 + wrow + lg * 4 + rg;
                    if (g < n) out[(size_t)g * 170 + 32 + lr] = p[rg] + bpv;
                }
            }
        }
#pragma unroll
        for (int ct = 0; ct < 8; ++ct) {
            float bv = bd1[ct * 16 + lr];
#pragma unroll
            for (int rg = 0; rg < 4; ++rg) {
                float v = fmaxf(acc[ct][rg] + bv, 0.f);
                u16 vh = bfhi(v), vl = bfhi(v - bf2f(vh));
                int rr = wrow + lg * 4 + rg, cc = ct * 16 + lr;
                hH[rr][cc] = vh; hL[rr][cc] = vl;
            }
        }
    }
    __syncthreads();   // all waves done reading stage-1 weights

    // ---- stage Wd2 (tiles 8..39 -> slots 0..31) ----
    for (int i = tid; i < 32 * 64; i += 256) {
        ((int4*)wbH)[i] = ((const int4*)whi)[8 * 64 + i];
        ((int4*)wbL)[i] = ((const int4*)wlo)[8 * 64 + i];
    }
    __syncthreads();

    // ---- stage 2: h2 = relu(h1 @ Wd2 + bd2) (K=128) ----
    {
#pragma unroll
        for (int ct = 0; ct < 8; ++ct) acc[ct] = (f4){0.f, 0.f, 0.f, 0.f};
#pragma unroll
        for (int kt = 0; kt < 4; ++kt) {
            bf8 aH = *(const bf8*)&hH[wrow + lr][kt * 32 + lg * 8];
            bf8 aL = *(const bf8*)&hL[wrow + lr][kt * 32 + lg * 8];
#pragma unroll
            for (int ct = 0; ct < 8; ++ct) {
                bf8 bH = *(const bf8*)&wbH[kt * 8 + ct][l * 8];
                bf8 bL = *(const bf8*)&wbL[kt * 8 + ct][l * 8];
                acc[ct] = __builtin_amdgcn_mfma_f32_16x16x32_bf16(aH, bH, acc[ct], 0, 0, 0);
                acc[ct] = __builtin_amdgcn_mfma_f32_16x16x32_bf16(aL, bH, acc[ct], 0, 0, 0);
                acc[ct] = __builtin_amdgcn_mfma_f32_16x16x32_bf16(aH, bL, acc[ct], 0, 0, 0);
            }
        }
        // write h2 (own-wave rows; all h1 reads above precede in program order)
#pragma unroll
        for (int ct = 0; ct < 8; ++ct) {
            float bv = bd2[ct * 16 + lr];
#pragma unroll
            for (int rg = 0; rg < 4; ++rg) {
                float v = fmaxf(acc[ct][rg] + bv, 0.f);
                u16 vh = bfhi(v), vl = bfhi(v - bf2f(vh));
                int rr = wrow + lg * 4 + rg, cc = ct * 16 + lr;
                hH[rr][cc] = vh; hL[rr][cc] = vl;
            }
        }
    }
    __syncthreads();   // all waves done reading stage-2 weights

    // ---- stage Wd3 (tiles 40..71 -> slots 0..31) ----
    for (int i = tid; i < 32 * 64; i += 256) {
        ((int4*)wbH)[i] = ((const int4*)whi)[40 * 64 + i];
        ((int4*)wbL)[i] = ((const int4*)wlo)[40 * 64 + i];
    }
    __syncthreads();

    // ---- stage 3: dec = softplus(h2 @ Wd3 + bd3) -> out[:,42:170) ----
    {
#pragma unroll
        for (int ct = 0; ct < 8; ++ct) acc[ct] = (f4){0.f, 0.f, 0.f, 0.f};
#pragma unroll
        for (int kt = 0; kt < 4; ++kt) {
            bf8 aH = *(const bf8*)&hH[wrow + lr][kt * 32 + lg * 8];
            bf8 aL = *(const bf8*)&hL[wrow + lr][kt * 32 + lg * 8];
#pragma unroll
            for (int ct = 0; ct < 8; ++ct) {
                bf8 bH = *(const bf8*)&wbH[kt * 8 + ct][l * 8];
                bf8 bL = *(const bf8*)&wbL[kt * 8 + ct][l * 8];
                acc[ct] = __builtin_amdgcn_mfma_f32_16x16x32_bf16(aH, bH, acc[ct], 0, 0, 0);
                acc[ct] = __builtin_amdgcn_mfma_f32_16x16x32_bf16(aL, bH, acc[ct], 0, 0, 0);
                acc[ct] = __builtin_amdgcn_mfma_f32_16x16x32_bf16(aH, bL, acc[ct], 0, 0, 0);
            }
        }
#pragma unroll
        for (int ct = 0; ct < 8; ++ct) {
            float bv = bd3[ct * 16 + lr];
#pragma unroll
            for (int rg = 0; rg < 4; ++rg) {
                int g = row0 + wrow + lg * 4 + rg;
                if (g < n) {
                    float v = acc[ct][rg] + bv;
                    v = fmaxf(v, 0.f) + log1pf(expf(-fabsf(v)));
                    out[(size_t)g * 170 + 42 + ct * 16 + lr] = v;
                }
            }
        }
    }
}

// ---------------- launch ----------------

extern "C" void kernel_launch(void* const* d_in, const int* in_sizes, int n_in,
                              void* d_out, int out_size, void* d_ws, size_t ws_size,
                              hipStream_t stream) {
    const float* raw_x = (const float*)d_in[0];
    const int*   ei    = (const int*)d_in[1];
    const float* W1 = (const float*)d_in[2];  const float* b1 = (const float*)d_in[3];
    const float* W2 = (const float*)d_in[4];  const float* b2 = (const float*)d_in[5];
    const float* Wp = (const float*)d_in[6];  const float* bp = (const float*)d_in[7];
    const float* Wd1 = (const float*)d_in[8]; const float* bd1 = (const float*)d_in[9];
    const float* Wd2 = (const float*)d_in[10]; const float* bd2 = (const float*)d_in[11];
    const float* Wd3 = (const float*)d_in[12]; const float* bd3 = (const float*)d_in[13];

    const int n = in_sizes[0] / 128;   // 50000
    const int E = in_sizes[1] / 2;     // 800000
    const int* row = ei;        // source
    const int* col = ei + E;    // target

    float* out = (float*)d_out;

    // workspace layout
    char* ws = (char*)d_ws;
    int*   deg    = (int*)ws;                        ws += (size_t)n * 4;
    float* dinv   = (float*)ws;                      ws += (size_t)n * 4;
    int*   rowptr = (int*)ws;                        ws += (size_t)(n + 4) * 4;
    int*   cursor = (int*)ws;                        ws += (size_t)n * 4;
    int*   bsum   = (int*)ws;                        ws += 64 * 4;
    int*   bpre   = (int*)ws;                        ws += 64 * 4;
    int*   csrc   = (int*)ws;                        ws += (size_t)E * 4;
    float* hs1    = (float*)ws;                      // [n,64]
    float* x1     = hs1 + (size_t)n * 64;            // [n,64]
    float* hs2    = x1 + (size_t)n * 64;             // [n,32]
    u16*   wswHi  = (u16*)(hs2 + (size_t)n * 32);    // 73*512 u16
    u16*   wswLo  = wswHi + 73 * 512;

    const int BS = 256;
    auto blocks = [](long long work, int bs) { return (unsigned)((work + bs - 1) / bs); };
    const int nb = (n + 1023) / 1024;                // scan blocks (49)

    // ---- graph structure (CSR by target) + weight swizzle ----
    hipMemsetAsync(deg, 0, (size_t)n * 4, stream);
    wswz_kernel<<<73, 64, 0, stream>>>(Wd1, Wd2, Wd3, Wp, wswHi, wswLo);
    deg_kernel<<<blocks(E, BS), BS, 0, stream>>>(col, deg, E);
    dinv_kernel<<<blocks(n, BS), BS, 0, stream>>>(deg, dinv, n);
    scan_phase1<<<nb, 256, 0, stream>>>(deg, bsum, n);
    scan_phase2<<<1, 64, 0, stream>>>(bsum, bpre, nb, rowptr, n, E);
    scan_phase3<<<nb, 256, 0, stream>>>(deg, bpre, rowptr, cursor, n);
    fill_kernel<<<blocks(E, BS), BS, 0, stream>>>(row, col, cursor, csrc, E);

    // ---- GCN layer 1: raw_x[128] -> 64 ----
    gemm_gcn<128, 64><<<blocks(n, 64), 256, 0, stream>>>(raw_x, W1, dinv, hs1, n);
    agg_finalize<64, true><<<blocks((long long)n * 16, BS), BS, 0, stream>>>(
        rowptr, csrc, hs1, dinv, b1, x1, n, 64, 0);

    // ---- GCN layer 2: x1[64] -> 32 ----
    gemm_gcn<64, 32><<<blocks(n, 64), 256, 0, stream>>>(x1, W2, dinv, hs2, n);
    agg_finalize<32, false><<<blocks((long long)n * 8, BS), BS, 0, stream>>>(
        rowptr, csrc, hs2, dinv, b2, out, n, 170, 0);   // emb -> out[:,0:32)

    // ---- fused MFMA decoder: head + 3 dense layers ----
    decoder_mfma<<<blocks(n, 64), 256, 0, stream>>>(
        out, wswHi, wswLo, bp, bd1, bd2, bd3, out, n);
}

// Round 10
// 309.976 us; speedup vs baseline: 1.1035x; 1.0439x over previous
//
#include <hip/hip_runtime.h>
#include <math.h>

typedef unsigned short u16;
typedef unsigned int u32;
typedef __attribute__((ext_vector_type(8))) short bf8;   // 8 bf16 = 4 VGPR
typedef __attribute__((ext_vector_type(4))) float f4;    // 4 f32 acc

__device__ __forceinline__ u16 bfhi(float x) {
    u32 u = __float_as_uint(x);
    u32 r = u + 0x7FFFu + ((u >> 16) & 1u);   // RNE
    return (u16)(r >> 16);
}
__device__ __forceinline__ float bf2f(u16 h) { return __uint_as_float(((u32)h) << 16); }

// ---------------- degree / norm ----------------

__global__ void deg_kernel(const int* __restrict__ col, int* __restrict__ deg, int E) {
    int e = blockIdx.x * blockDim.x + threadIdx.x;
    if (e < E) atomicAdd(&deg[col[e]], 1);
}

__global__ void dinv_kernel(const int* __restrict__ deg, float* __restrict__ dinv, int n) {
    int i = blockIdx.x * blockDim.x + threadIdx.x;
    if (i < n) dinv[i] = 1.0f / sqrtf((float)(deg[i] + 1));  // +1 self loop
}

// ---------------- 3-phase scan: deg -> rowptr/cursor ----------------
__global__ void scan_phase1(const int* __restrict__ deg, int* __restrict__ bsum, int n) {
    __shared__ int red[256];
    int tid = threadIdx.x;
    int base = blockIdx.x * 1024 + tid * 4;
    int s = 0;
    if (base + 3 < n) { int4 v = *(const int4*)&deg[base]; s = v.x + v.y + v.z + v.w; }
    else { for (int i = 0; i < 4; ++i) if (base + i < n) s += deg[base + i]; }
    red[tid] = s; __syncthreads();
    for (int off = 128; off > 0; off >>= 1) { if (tid < off) red[tid] += red[tid + off]; __syncthreads(); }
    if (tid == 0) bsum[blockIdx.x] = red[0];
}

__global__ void scan_phase2(const int* __restrict__ bsum, int* __restrict__ bpre,
                            int nb, int* __restrict__ rowptr, int n, int E) {
    int tid = threadIdx.x;  // 64 threads
    int sv = (tid < nb) ? bsum[tid] : 0;
    int v = sv;
    for (int off = 1; off < 64; off <<= 1) {
        int w = __shfl_up(v, off);
        if (tid >= off) v += w;
    }
    if (tid < nb) bpre[tid] = v - sv;   // exclusive
    if (tid == 0) rowptr[n] = E;
}

__global__ void scan_phase3(const int* __restrict__ deg, const int* __restrict__ bpre,
                            int* __restrict__ rowptr, int* __restrict__ cursor, int n) {
    __shared__ int tsum[256];
    int tid = threadIdx.x;
    int base = blockIdx.x * 1024 + tid * 4;
    int d[4] = {0, 0, 0, 0};
    if (base + 3 < n) { int4 v = *(const int4*)&deg[base]; d[0] = v.x; d[1] = v.y; d[2] = v.z; d[3] = v.w; }
    else { for (int i = 0; i < 4; ++i) if (base + i < n) d[i] = deg[base + i]; }
    int s = d[0] + d[1] + d[2] + d[3];
    tsum[tid] = s; __syncthreads();
    for (int off = 1; off < 256; off <<= 1) {
        int v = tsum[tid];
        int w = (tid >= off) ? tsum[tid - off] : 0;
        __syncthreads();
        tsum[tid] = v + w;
        __syncthreads();
    }
    int pre = bpre[blockIdx.x] + tsum[tid] - s;
    for (int i = 0; i < 4; ++i) {
        int idx = base + i;
        if (idx < n) { rowptr[idx] = pre; cursor[idx] = pre; pre += d[i]; }
    }
}

__global__ void fill_kernel(const int* __restrict__ row, const int* __restrict__ col,
                            int* __restrict__ cursor, int* __restrict__ csrc, int E) {
    int e = blockIdx.x * blockDim.x + threadIdx.x;
    if (e < E) {
        int c = col[e];
        int slot = atomicAdd(&cursor[c], 1);
        csrc[slot] = row[e];
    }
}

// ---------------- CSR gather aggregation + finalize ----------------
template<int F, bool OV>
__global__ void agg_finalize(const int* __restrict__ rowptr, const int* __restrict__ csrc,
                             const float* __restrict__ hs, const float* __restrict__ dinv,
                             const float* __restrict__ b, float* __restrict__ out,
                             int n, int ostride, int col0) {
    constexpr int L = F / 4;                 // lanes per node
    int tid = blockIdx.x * blockDim.x + threadIdx.x;
    int node = tid / L, lane = tid % L;
    if (node >= n) return;
    int f0 = lane * 4;
    int beg = rowptr[node], end = rowptr[node + 1];
    float4 sum = make_float4(0.f, 0.f, 0.f, 0.f);
    for (int j = beg; j < end; ++j) {
        int s = csrc[j];                     // uniform across the L-lane group
        float4 v = *(const float4*)&hs[(size_t)s * F + f0];
        sum.x += v.x; sum.y += v.y; sum.z += v.z; sum.w += v.w;
    }
    float4 self = *(const float4*)&hs[(size_t)node * F + f0];
    float di = dinv[node];
    float r0 = fmaxf(di * (sum.x + self.x) + b[f0 + 0], 0.f);
    float r1 = fmaxf(di * (sum.y + self.y) + b[f0 + 1], 0.f);
    float r2 = fmaxf(di * (sum.z + self.z) + b[f0 + 2], 0.f);
    float r3 = fmaxf(di * (sum.w + self.w) + b[f0 + 3], 0.f);
    float* op = &out[(size_t)node * ostride + col0 + f0];
    if (OV) {
        *(float4*)op = make_float4(r0, r1, r2, r3);
    } else {
        op[0] = r0; op[1] = r1; op[2] = r2; op[3] = r3;
    }
}

// ---------------- GCN dense: out[r,c] = dinv[r] * sum_k x[r,k]*W[k,c] ----------------
template<int K, int OC>
__global__ __launch_bounds__(256) void gemm_gcn(
    const float* __restrict__ x, const float* __restrict__ W,
    const float* __restrict__ dinv, float* __restrict__ outp, int n) {
    constexpr int CG = OC / 8;        // col groups
    constexpr int RG = 256 / CG;      // row groups
    constexpr int ROWS = 64 / RG;     // rows per thread
    __shared__ float xL[64][K + 4];

    const int tid = threadIdx.x;
    const int cg = tid % CG, rg = tid / CG;
    const int c0 = cg * 8, r0 = rg * ROWS;
    const int row0 = blockIdx.x * 64;

#pragma unroll
    for (int i = 0; i < K / 16; ++i) {
        int e = tid + i * 256;
        int r = e / (K / 4), q = e % (K / 4);
        float4 v = make_float4(0.f, 0.f, 0.f, 0.f);
        if (row0 + r < n) v = *(const float4*)&x[(size_t)(row0 + r) * K + q * 4];
        *(float4*)&xL[r][q * 4] = v;
    }
    __syncthreads();

    float acc[ROWS][8];
#pragma unroll
    for (int r = 0; r < ROWS; ++r)
#pragma unroll
        for (int c = 0; c < 8; ++c) acc[r][c] = 0.f;

#pragma unroll 8
    for (int k = 0; k < K; ++k) {
        float4 w0 = *(const float4*)&W[(size_t)k * OC + c0];
        float4 w1 = *(const float4*)&W[(size_t)k * OC + c0 + 4];
        float wv[8] = {w0.x, w0.y, w0.z, w0.w, w1.x, w1.y, w1.z, w1.w};
        float xv[ROWS];
#pragma unroll
        for (int r = 0; r < ROWS; ++r) xv[r] = xL[r0 + r][k];
#pragma unroll
        for (int r = 0; r < ROWS; ++r)
#pragma unroll
            for (int c = 0; c < 8; ++c) acc[r][c] = fmaf(xv[r], wv[c], acc[r][c]);
    }

#pragma unroll
    for (int r = 0; r < ROWS; ++r) {
        int gr = row0 + r0 + r;
        if (gr >= n) continue;
        float di = dinv[gr];
        float* op = &outp[(size_t)gr * OC + c0];
        *(float4*)op = make_float4(acc[r][0] * di, acc[r][1] * di, acc[r][2] * di, acc[r][3] * di);
        *(float4*)(op + 4) = make_float4(acc[r][4] * di, acc[r][5] * di, acc[r][6] * di, acc[r][7] * di);
    }
}

// ---------------- weight pre-swizzle into MFMA B-fragment order ----------------
// B-frag for mfma_f32_16x16x32_bf16: lane l holds B[kt*32 + (l>>4)*8 + j][ct*16 + (l&15)], j=0..7
// tiles: 0..7 Wd1(32x128), 8..39 Wd2(128x128), 40..71 Wd3(128x128), 72 Wp(32x10 pad16)
__global__ void wswz_kernel(const float* __restrict__ Wd1, const float* __restrict__ Wd2,
                            const float* __restrict__ Wd3, const float* __restrict__ Wp,
                            u16* __restrict__ whi, u16* __restrict__ wlo) {
    int t = blockIdx.x, l = threadIdx.x;   // 73 blocks x 64 threads
    const float* W; int C, kt, ct;
    if (t < 8)       { W = Wd1; C = 128; kt = 0;           ct = t; }
    else if (t < 40) { W = Wd2; C = 128; kt = (t - 8) >> 3; ct = (t - 8) & 7; }
    else if (t < 72) { W = Wd3; C = 128; kt = (t - 40) >> 3; ct = (t - 40) & 7; }
    else             { W = Wp;  C = 10;  kt = 0;           ct = 0; }
    int kbase = kt * 32 + (l >> 4) * 8;
    int c = ct * 16 + (l & 15);
    size_t base = (size_t)t * 512 + (size_t)l * 8;
#pragma unroll
    for (int j = 0; j < 8; ++j) {
        float v = (c < C) ? W[(size_t)(kbase + j) * C + c] : 0.f;
        u16 h = bfhi(v);
        whi[base + j] = (u16)h;
        wlo[base + j] = bfhi(v - bf2f(h));
    }
}

// ---------------- decoder stage 1: h1 = relu(emb @ Wd1 + bd1), + head ----------------
// Grid-stride over 64-row tiles. Weights (9 tiles) staged once per block.
__global__ __launch_bounds__(256, 2) void dec_stage1(
    const float* __restrict__ obuf,
    const u16* __restrict__ whi, const u16* __restrict__ wlo,
    const float* __restrict__ bp, const float* __restrict__ bd1,
    u16* __restrict__ h1H, u16* __restrict__ h1L,
    float* __restrict__ out, int n, int ntiles) {
    __shared__ __align__(16) u16 wbH[9][512], wbL[9][512];
    const int tid = threadIdx.x;
    const int l = tid & 63, wv = tid >> 6;
    const int lr = l & 15, lg = l >> 4;

    for (int i = tid; i < 9 * 64; i += 256) {
        int tl = i >> 6, e = i & 63;
        int st = (tl < 8) ? tl : 72;
        ((int4*)wbH)[i] = ((const int4*)whi)[(st << 6) + e];
        ((int4*)wbL)[i] = ((const int4*)wlo)[(st << 6) + e];
    }
    __syncthreads();

    for (int t = blockIdx.x; t < ntiles; t += gridDim.x) {
        const int row0 = t * 64;
        int arow = row0 + wv * 16 + lr; if (arow >= n) arow = n - 1;   // clamp (extra rows discarded)
        const float* src = &obuf[(size_t)arow * 170 + lg * 8];
        bf8 aH, aL;
#pragma unroll
        for (int i = 0; i < 8; i += 2) {
            float2 v = *(const float2*)(src + i);
            u16 h0 = bfhi(v.x), h1 = bfhi(v.y);
            ((u16*)&aH)[i] = h0;     ((u16*)&aH)[i + 1] = h1;
            ((u16*)&aL)[i] = bfhi(v.x - bf2f(h0));
            ((u16*)&aL)[i + 1] = bfhi(v.y - bf2f(h1));
        }
        f4 acc[8];
#pragma unroll
        for (int ct = 0; ct < 8; ++ct) {
            bf8 bH = *(const bf8*)&wbH[ct][l * 8];
            bf8 bL = *(const bf8*)&wbL[ct][l * 8];
            f4 a = (f4){0.f, 0.f, 0.f, 0.f};
            a = __builtin_amdgcn_mfma_f32_16x16x32_bf16(aH, bH, a, 0, 0, 0);
            a = __builtin_amdgcn_mfma_f32_16x16x32_bf16(aL, bH, a, 0, 0, 0);
            a = __builtin_amdgcn_mfma_f32_16x16x32_bf16(aH, bL, a, 0, 0, 0);
            acc[ct] = a;
        }
        {   // head (staged slot 8 = Wp)
            bf8 pH = *(const bf8*)&wbH[8][l * 8];
            bf8 pL = *(const bf8*)&wbL[8][l * 8];
            f4 p = (f4){0.f, 0.f, 0.f, 0.f};
            p = __builtin_amdgcn_mfma_f32_16x16x32_bf16(aH, pH, p, 0, 0, 0);
            p = __builtin_amdgcn_mfma_f32_16x16x32_bf16(aL, pH, p, 0, 0, 0);
            p = __builtin_amdgcn_mfma_f32_16x16x32_bf16(aH, pL, p, 0, 0, 0);
            if (lr < 10) {
                float bpv = bp[lr];
#pragma unroll
                for (int rg = 0; rg < 4; ++rg) {
                    int g = row0 + wv * 16 + lg * 4 + rg;
                    if (g < n) out[(size_t)g * 170 + 32 + lr] = p[rg] + bpv;
                }
            }
        }
#pragma unroll
        for (int ct = 0; ct < 8; ++ct) {
            float bv = bd1[ct * 16 + lr];
#pragma unroll
            for (int rg = 0; rg < 4; ++rg) {
                int g = row0 + wv * 16 + lg * 4 + rg;
                if (g < n) {
                    float v = fmaxf(acc[ct][rg] + bv, 0.f);
                    u16 vh = bfhi(v);
                    h1H[(size_t)g * 128 + ct * 16 + lr] = vh;
                    h1L[(size_t)g * 128 + ct * 16 + lr] = bfhi(v - bf2f(vh));
                }
            }
        }
    }
}

// ---------------- decoder stages 2/3: K=128 GEMM from bf16 planes ----------------
// TBASE: first swizzled tile (8=Wd2, 40=Wd3). ACT 1: relu -> planes; ACT 2: softplus -> out[:,42:170).
template<int TBASE, int ACT>
__global__ __launch_bounds__(256, 2) void dec_stage128(
    const u16* __restrict__ whi, const u16* __restrict__ wlo,
    const u16* __restrict__ inH, const u16* __restrict__ inL,
    const float* __restrict__ bias,
    u16* __restrict__ outH, u16* __restrict__ outL,
    float* __restrict__ out, int n, int ntiles) {
    __shared__ __align__(16) u16 wbH[32][512], wbL[32][512];   // 64 KB
    const int tid = threadIdx.x;
    const int l = tid & 63, wv = tid >> 6;
    const int lr = l & 15, lg = l >> 4;

    for (int i = tid; i < 32 * 64; i += 256) {
        ((int4*)wbH)[i] = ((const int4*)whi)[TBASE * 64 + i];
        ((int4*)wbL)[i] = ((const int4*)wlo)[TBASE * 64 + i];
    }
    __syncthreads();

    for (int t = blockIdx.x; t < ntiles; t += gridDim.x) {
        const int row0 = t * 64;
        int arow = row0 + wv * 16 + lr; if (arow >= n) arow = n - 1;
        const u16* pH = &inH[(size_t)arow * 128 + lg * 8];
        const u16* pL = &inL[(size_t)arow * 128 + lg * 8];
        f4 acc[8];
#pragma unroll
        for (int ct = 0; ct < 8; ++ct) acc[ct] = (f4){0.f, 0.f, 0.f, 0.f};
#pragma unroll
        for (int kt = 0; kt < 4; ++kt) {
            bf8 aH = *(const bf8*)(pH + kt * 32);
            bf8 aL = *(const bf8*)(pL + kt * 32);
#pragma unroll
            for (int ct = 0; ct < 8; ++ct) {
                bf8 bH = *(const bf8*)&wbH[kt * 8 + ct][l * 8];
                bf8 bL = *(const bf8*)&wbL[kt * 8 + ct][l * 8];
                acc[ct] = __builtin_amdgcn_mfma_f32_16x16x32_bf16(aH, bH, acc[ct], 0, 0, 0);
                acc[ct] = __builtin_amdgcn_mfma_f32_16x16x32_bf16(aL, bH, acc[ct], 0, 0, 0);
                acc[ct] = __builtin_amdgcn_mfma_f32_16x16x32_bf16(aH, bL, acc[ct], 0, 0, 0);
            }
        }
#pragma unroll
        for (int ct = 0; ct < 8; ++ct) {
            float bv = bias[ct * 16 + lr];
#pragma unroll
            for (int rg = 0; rg < 4; ++rg) {
                int g = row0 + wv * 16 + lg * 4 + rg;
                if (g < n) {
                    float v = acc[ct][rg] + bv;
                    if (ACT == 1) {
                        v = fmaxf(v, 0.f);
                        u16 vh = bfhi(v);
                        outH[(size_t)g * 128 + ct * 16 + lr] = vh;
                        outL[(size_t)g * 128 + ct * 16 + lr] = bfhi(v - bf2f(vh));
                    } else {
                        v = fmaxf(v, 0.f) + __logf(1.f + __expf(-fabsf(v)));
                        out[(size_t)g * 170 + 42 + ct * 16 + lr] = v;
                    }
                }
            }
        }
    }
}

// ---------------- launch ----------------

extern "C" void kernel_launch(void* const* d_in, const int* in_sizes, int n_in,
                              void* d_out, int out_size, void* d_ws, size_t ws_size,
                              hipStream_t stream) {
    const float* raw_x = (const float*)d_in[0];
    const int*   ei    = (const int*)d_in[1];
    const float* W1 = (const float*)d_in[2];  const float* b1 = (const float*)d_in[3];
    const float* W2 = (const float*)d_in[4];  const float* b2 = (const float*)d_in[5];
    const float* Wp = (const float*)d_in[6];  const float* bp = (const float*)d_in[7];
    const float* Wd1 = (const float*)d_in[8]; const float* bd1 = (const float*)d_in[9];
    const float* Wd2 = (const float*)d_in[10]; const float* bd2 = (const float*)d_in[11];
    const float* Wd3 = (const float*)d_in[12]; const float* bd3 = (const float*)d_in[13];

    const int n = in_sizes[0] / 128;   // 50000
    const int E = in_sizes[1] / 2;     // 800000
    const int* row = ei;        // source
    const int* col = ei + E;    // target

    float* out = (float*)d_out;

    // workspace layout
    char* ws = (char*)d_ws;
    int*   deg    = (int*)ws;                        ws += (size_t)n * 4;
    float* dinv   = (float*)ws;                      ws += (size_t)n * 4;
    int*   rowptr = (int*)ws;                        ws += (size_t)(n + 4) * 4;
    int*   cursor = (int*)ws;                        ws += (size_t)n * 4;
    int*   bsum   = (int*)ws;                        ws += 64 * 4;
    int*   bpre   = (int*)ws;                        ws += 64 * 4;
    int*   csrc   = (int*)ws;                        ws += (size_t)E * 4;
    float* hs1    = (float*)ws;                      // [n,64] f32
    float* x1     = hs1 + (size_t)n * 64;            // [n,64] f32
    float* hs2    = x1 + (size_t)n * 64;             // [n,32] f32
    u16*   wswHi  = (u16*)(hs2 + (size_t)n * 32);    // 73*512 u16
    u16*   wswLo  = wswHi + 73 * 512;
    u16*   h1H    = (u16*)hs1;                       // [n,128] u16 (overlays hs1 — dead by decoder)
    u16*   h1L    = (u16*)x1;                        // [n,128] u16 (overlays x1 — dead by decoder)
    u16*   h2H    = wswLo + 73 * 512;                // [n,128] u16
    u16*   h2L    = h2H + (size_t)n * 128;           // [n,128] u16

    const int BS = 256;
    auto blocks = [](long long work, int bs) { return (unsigned)((work + bs - 1) / bs); };
    const int nb = (n + 1023) / 1024;                // scan blocks (49)
    const int ntiles = (n + 63) / 64;                // 782

    // ---- graph structure (CSR by target) + weight swizzle ----
    hipMemsetAsync(deg, 0, (size_t)n * 4, stream);
    wswz_kernel<<<73, 64, 0, stream>>>(Wd1, Wd2, Wd3, Wp, wswHi, wswLo);
    deg_kernel<<<blocks(E, BS), BS, 0, stream>>>(col, deg, E);
    dinv_kernel<<<blocks(n, BS), BS, 0, stream>>>(deg, dinv, n);
    scan_phase1<<<nb, 256, 0, stream>>>(deg, bsum, n);
    scan_phase2<<<1, 64, 0, stream>>>(bsum, bpre, nb, rowptr, n, E);
    scan_phase3<<<nb, 256, 0, stream>>>(deg, bpre, rowptr, cursor, n);
    fill_kernel<<<blocks(E, BS), BS, 0, stream>>>(row, col, cursor, csrc, E);

    // ---- GCN layer 1: raw_x[128] -> 64 ----
    gemm_gcn<128, 64><<<blocks(n, 64), 256, 0, stream>>>(raw_x, W1, dinv, hs1, n);
    agg_finalize<64, true><<<blocks((long long)n * 16, BS), BS, 0, stream>>>(
        rowptr, csrc, hs1, dinv, b1, x1, n, 64, 0);

    // ---- GCN layer 2: x1[64] -> 32 ----
    gemm_gcn<64, 32><<<blocks(n, 64), 256, 0, stream>>>(x1, W2, dinv, hs2, n);
    agg_finalize<32, false><<<blocks((long long)n * 8, BS), BS, 0, stream>>>(
        rowptr, csrc, hs2, dinv, b2, out, n, 170, 0);   // emb -> out[:,0:32)
    // NOTE: hs1/x1 are dead from here -> reused as h1 planes.

    // ---- decoder: 3 compact looped MFMA kernels ----
    dec_stage1<<<512, 256, 0, stream>>>(out, wswHi, wswLo, bp, bd1, h1H, h1L, out, n, ntiles);
    dec_stage128<8, 1><<<512, 256, 0, stream>>>(wswHi, wswLo, h1H, h1L, bd2, h2H, h2L, nullptr, n, ntiles);
    dec_stage128<40, 2><<<512, 256, 0, stream>>>(wswHi, wswLo, h2H, h2L, bd3, nullptr, nullptr, out, n, ntiles);
}

// Round 11
// 284.534 us; speedup vs baseline: 1.2022x; 1.0894x over previous
//
#include <hip/hip_runtime.h>
#include <math.h>

typedef unsigned short u16;
typedef unsigned int u32;
typedef __attribute__((ext_vector_type(8))) short bf8;   // 8 bf16 = 4 VGPR
typedef __attribute__((ext_vector_type(4))) float f4;    // 4 f32 acc

__device__ __forceinline__ u16 bfhi(float x) {
    u32 u = __float_as_uint(x);
    u32 r = u + 0x7FFFu + ((u >> 16) & 1u);   // RNE
    return (u16)(r >> 16);
}
__device__ __forceinline__ float bf2f(u16 h) { return __uint_as_float(((u32)h) << 16); }

// ================= graph build: zero-global-atomic bucketed CSR =================
// bucket = col >> 6 (64 nodes per bucket). CH = 8192 edges per workgroup.

__global__ __launch_bounds__(256) void bucket_hist(const int* __restrict__ col,
                                                   int* __restrict__ M, int E, int nbuk, int nwg) {
    __shared__ int h[1024];
    const int tid = threadIdx.x;
    for (int i = tid; i < 1024; i += 256) h[i] = 0;
    __syncthreads();
    int base = blockIdx.x * 8192;
    for (int i = tid; i < 8192; i += 256) {
        int e = base + i;
        if (e < E) atomicAdd(&h[col[e] >> 6], 1);   // LDS atomic
    }
    __syncthreads();
    for (int b = tid; b < nbuk; b += 256) M[b * nwg + blockIdx.x] = h[b];
}

// per-bucket exclusive scan over workgroups (in place), bucket totals -> bsum
__global__ void col_scan(int* __restrict__ M, int* __restrict__ bsum, int nbuk, int nwg) {
    int b = blockIdx.x * blockDim.x + threadIdx.x;
    if (b >= nbuk) return;
    int s = 0;
    for (int w = 0; w < nwg; ++w) { int t = M[b * nwg + w]; M[b * nwg + w] = s; s += t; }
    bsum[b] = s;
}

// single block: exclusive scan of bucket sums -> boff; boff[nbuk]=E; rowptr[n]=E
__global__ void bucket_scan(const int* __restrict__ bsum, int* __restrict__ boff,
                            int* __restrict__ rowptr, int nbuk, int n, int E) {
    __shared__ int sh[1024];
    const int tid = threadIdx.x;
    int v = (tid < nbuk) ? bsum[tid] : 0;
    sh[tid] = v; __syncthreads();
    for (int off = 1; off < 1024; off <<= 1) {
        int x = sh[tid];
        int w = (tid >= off) ? sh[tid - off] : 0;
        __syncthreads();
        sh[tid] = x + w;
        __syncthreads();
    }
    if (tid < nbuk) boff[tid] = sh[tid] - v;
    if (tid == 0) { boff[nbuk] = E; rowptr[n] = E; }
}

// scatter edges into bucket-sorted ebuf (LDS ranks, no global atomics)
__global__ __launch_bounds__(256) void bucket_scatter(const int* __restrict__ row,
                                                      const int* __restrict__ col,
                                                      const int* __restrict__ M,
                                                      const int* __restrict__ boff,
                                                      int2* __restrict__ ebuf, int E, int nwg) {
    __shared__ int h[1024];
    const int tid = threadIdx.x;
    for (int i = tid; i < 1024; i += 256) h[i] = 0;
    __syncthreads();
    int base = blockIdx.x * 8192;
    for (int i = tid; i < 8192; i += 256) {
        int e = base + i;
        if (e < E) {
            int c = col[e], b = c >> 6;
            int rank = atomicAdd(&h[b], 1);  // LDS
            int slot = boff[b] + M[b * nwg + blockIdx.x] + rank;
            ebuf[slot] = make_int2(c, row[e]);
        }
    }
}

// per-bucket: node histogram -> dinv + rowptr + node-sorted csrc (all bucket-local)
__global__ __launch_bounds__(256) void bucket_finalize(const int2* __restrict__ ebuf,
                                                       const int* __restrict__ boff,
                                                       int* __restrict__ rowptr,
                                                       int* __restrict__ csrc,
                                                       float* __restrict__ dinv, int n) {
    __shared__ int h[64];
    __shared__ int curs[64];
    const int b = blockIdx.x, tid = threadIdx.x;
    const int n0 = b << 6;
    const int beg = boff[b], end = boff[b + 1];
    if (tid < 64) h[tid] = 0;
    __syncthreads();
    for (int i = beg + tid; i < end; i += 256) atomicAdd(&h[ebuf[i].x & 63], 1);
    __syncthreads();
    if (tid < 64) {                    // first wave: 64-lane shfl scan
        int cnt = h[tid];
        int v = cnt;
        for (int off = 1; off < 64; off <<= 1) {
            int w = __shfl_up(v, off);
            if (tid >= off) v += w;
        }
        int cursor = beg + v - cnt;    // exclusive
        curs[tid] = cursor;
        int node = n0 + tid;
        if (node < n) {
            rowptr[node] = cursor;
            dinv[node] = rsqrtf((float)(cnt + 1));   // +1 self loop
        }
    }
    __syncthreads();
    for (int i = beg + tid; i < end; i += 256) {
        int2 e = ebuf[i];
        int slot = atomicAdd(&curs[e.x & 63], 1);    // LDS
        csrc[slot] = e.y;
    }
}

// ---------------- CSR gather aggregation + finalize ----------------
template<int F, bool OV>
__global__ void agg_finalize(const int* __restrict__ rowptr, const int* __restrict__ csrc,
                             const float* __restrict__ hs, const float* __restrict__ dinv,
                             const float* __restrict__ b, float* __restrict__ out,
                             int n, int ostride, int col0) {
    constexpr int L = F / 4;                 // lanes per node
    int tid = blockIdx.x * blockDim.x + threadIdx.x;
    int node = tid / L, lane = tid % L;
    if (node >= n) return;
    int f0 = lane * 4;
    int beg = rowptr[node], end = rowptr[node + 1];
    float4 sum = make_float4(0.f, 0.f, 0.f, 0.f);
    for (int j = beg; j < end; ++j) {
        int s = csrc[j];                     // uniform across the L-lane group
        float4 v = *(const float4*)&hs[(size_t)s * F + f0];
        sum.x += v.x; sum.y += v.y; sum.z += v.z; sum.w += v.w;
    }
    float4 self = *(const float4*)&hs[(size_t)node * F + f0];
    float di = dinv[node];
    float r0 = fmaxf(di * (sum.x + self.x) + b[f0 + 0], 0.f);
    float r1 = fmaxf(di * (sum.y + self.y) + b[f0 + 1], 0.f);
    float r2 = fmaxf(di * (sum.z + self.z) + b[f0 + 2], 0.f);
    float r3 = fmaxf(di * (sum.w + self.w) + b[f0 + 3], 0.f);
    float* op = &out[(size_t)node * ostride + col0 + f0];
    if (OV) {
        *(float4*)op = make_float4(r0, r1, r2, r3);
    } else {
        op[0] = r0; op[1] = r1; op[2] = r2; op[3] = r3;
    }
}

// ---------------- GCN dense: out[r,c] = dinv[r] * sum_k x[r,k]*W[k,c] ----------------
template<int K, int OC>
__global__ __launch_bounds__(256) void gemm_gcn(
    const float* __restrict__ x, const float* __restrict__ W,
    const float* __restrict__ dinv, float* __restrict__ outp, int n) {
    constexpr int CG = OC / 8;        // col groups
    constexpr int RG = 256 / CG;      // row groups
    constexpr int ROWS = 64 / RG;     // rows per thread
    __shared__ float xL[64][K + 4];

    const int tid = threadIdx.x;
    const int cg = tid % CG, rg = tid / CG;
    const int c0 = cg * 8, r0 = rg * ROWS;
    const int row0 = blockIdx.x * 64;

#pragma unroll
    for (int i = 0; i < K / 16; ++i) {
        int e = tid + i * 256;
        int r = e / (K / 4), q = e % (K / 4);
        float4 v = make_float4(0.f, 0.f, 0.f, 0.f);
        if (row0 + r < n) v = *(const float4*)&x[(size_t)(row0 + r) * K + q * 4];
        *(float4*)&xL[r][q * 4] = v;
    }
    __syncthreads();

    float acc[ROWS][8];
#pragma unroll
    for (int r = 0; r < ROWS; ++r)
#pragma unroll
        for (int c = 0; c < 8; ++c) acc[r][c] = 0.f;

#pragma unroll 8
    for (int k = 0; k < K; ++k) {
        float4 w0 = *(const float4*)&W[(size_t)k * OC + c0];
        float4 w1 = *(const float4*)&W[(size_t)k * OC + c0 + 4];
        float wv[8] = {w0.x, w0.y, w0.z, w0.w, w1.x, w1.y, w1.z, w1.w};
        float xv[ROWS];
#pragma unroll
        for (int r = 0; r < ROWS; ++r) xv[r] = xL[r0 + r][k];
#pragma unroll
        for (int r = 0; r < ROWS; ++r)
#pragma unroll
            for (int c = 0; c < 8; ++c) acc[r][c] = fmaf(xv[r], wv[c], acc[r][c]);
    }

#pragma unroll
    for (int r = 0; r < ROWS; ++r) {
        int gr = row0 + r0 + r;
        if (gr >= n) continue;
        float di = dinv[gr];
        float* op = &outp[(size_t)gr * OC + c0];
        *(float4*)op = make_float4(acc[r][0] * di, acc[r][1] * di, acc[r][2] * di, acc[r][3] * di);
        *(float4*)(op + 4) = make_float4(acc[r][4] * di, acc[r][5] * di, acc[r][6] * di, acc[r][7] * di);
    }
}

// ---------------- weight pre-swizzle into MFMA B-fragment order ----------------
// B-frag for mfma_f32_16x16x32_bf16: lane l holds B[kt*32 + (l>>4)*8 + j][ct*16 + (l&15)], j=0..7
// tiles: 0..7 Wd1(32x128), 8..39 Wd2(128x128), 40..71 Wd3(128x128), 72 Wp(32x10 pad16)
__global__ void wswz_kernel(const float* __restrict__ Wd1, const float* __restrict__ Wd2,
                            const float* __restrict__ Wd3, const float* __restrict__ Wp,
                            u16* __restrict__ whi, u16* __restrict__ wlo) {
    int t = blockIdx.x, l = threadIdx.x;   // 73 blocks x 64 threads
    const float* W; int C, kt, ct;
    if (t < 8)       { W = Wd1; C = 128; kt = 0;           ct = t; }
    else if (t < 40) { W = Wd2; C = 128; kt = (t - 8) >> 3; ct = (t - 8) & 7; }
    else if (t < 72) { W = Wd3; C = 128; kt = (t - 40) >> 3; ct = (t - 40) & 7; }
    else             { W = Wp;  C = 10;  kt = 0;           ct = 0; }
    int kbase = kt * 32 + (l >> 4) * 8;
    int c = ct * 16 + (l & 15);
    size_t base = (size_t)t * 512 + (size_t)l * 8;
#pragma unroll
    for (int j = 0; j < 8; ++j) {
        float v = (c < C) ? W[(size_t)(kbase + j) * C + c] : 0.f;
        u16 h = bfhi(v);
        whi[base + j] = (u16)h;
        wlo[base + j] = bfhi(v - bf2f(h));
    }
}

// ---------------- decoder stage 1: h1 = relu(emb @ Wd1 + bd1), + head ----------------
// h1 written PACKED: u32 = hi | lo<<16 -> full-line coalesced stores.
__global__ __launch_bounds__(256, 2) void dec_stage1(
    const float* __restrict__ obuf,
    const u16* __restrict__ whi, const u16* __restrict__ wlo,
    const float* __restrict__ bp, const float* __restrict__ bd1,
    u32* __restrict__ h1P,
    float* __restrict__ out, int n, int ntiles) {
    __shared__ __align__(16) u16 wbH[9][512], wbL[9][512];
    const int tid = threadIdx.x;
    const int l = tid & 63, wv = tid >> 6;
    const int lr = l & 15, lg = l >> 4;

    for (int i = tid; i < 9 * 64; i += 256) {
        int tl = i >> 6, e = i & 63;
        int st = (tl < 8) ? tl : 72;
        ((int4*)wbH)[i] = ((const int4*)whi)[(st << 6) + e];
        ((int4*)wbL)[i] = ((const int4*)wlo)[(st << 6) + e];
    }
    __syncthreads();

    for (int t = blockIdx.x; t < ntiles; t += gridDim.x) {
        const int row0 = t * 64;
        int arow = row0 + wv * 16 + lr; if (arow >= n) arow = n - 1;   // clamp
        const float* src = &obuf[(size_t)arow * 170 + lg * 8];
        bf8 aH, aL;
#pragma unroll
        for (int i = 0; i < 8; i += 2) {
            float2 v = *(const float2*)(src + i);
            u16 h0 = bfhi(v.x), h1 = bfhi(v.y);
            ((u16*)&aH)[i] = h0;     ((u16*)&aH)[i + 1] = h1;
            ((u16*)&aL)[i] = bfhi(v.x - bf2f(h0));
            ((u16*)&aL)[i + 1] = bfhi(v.y - bf2f(h1));
        }
        f4 acc[8];
#pragma unroll
        for (int ct = 0; ct < 8; ++ct) {
            bf8 bH = *(const bf8*)&wbH[ct][l * 8];
            bf8 bL = *(const bf8*)&wbL[ct][l * 8];
            f4 a = (f4){0.f, 0.f, 0.f, 0.f};
            a = __builtin_amdgcn_mfma_f32_16x16x32_bf16(aH, bH, a, 0, 0, 0);
            a = __builtin_amdgcn_mfma_f32_16x16x32_bf16(aL, bH, a, 0, 0, 0);
            a = __builtin_amdgcn_mfma_f32_16x16x32_bf16(aH, bL, a, 0, 0, 0);
            acc[ct] = a;
        }
        {   // head (staged slot 8 = Wp)
            bf8 pH = *(const bf8*)&wbH[8][l * 8];
            bf8 pL = *(const bf8*)&wbL[8][l * 8];
            f4 p = (f4){0.f, 0.f, 0.f, 0.f};
            p = __builtin_amdgcn_mfma_f32_16x16x32_bf16(aH, pH, p, 0, 0, 0);
            p = __builtin_amdgcn_mfma_f32_16x16x32_bf16(aL, pH, p, 0, 0, 0);
            p = __builtin_amdgcn_mfma_f32_16x16x32_bf16(aH, pL, p, 0, 0, 0);
            if (lr < 10) {
                float bpv = bp[lr];
#pragma unroll
                for (int rg = 0; rg < 4; ++rg) {
                    int g = row0 + wv * 16 + lg * 4 + rg;
                    if (g < n) out[(size_t)g * 170 + 32 + lr] = p[rg] + bpv;
                }
            }
        }
#pragma unroll
        for (int ct = 0; ct < 8; ++ct) {
            float bv = bd1[ct * 16 + lr];
#pragma unroll
            for (int rg = 0; rg < 4; ++rg) {
                int g = row0 + wv * 16 + lg * 4 + rg;
                if (g < n) {
                    float v = fmaxf(acc[ct][rg] + bv, 0.f);
                    u16 vh = bfhi(v), vl = bfhi(v - bf2f(vh));
                    h1P[(size_t)g * 128 + ct * 16 + lr] = (u32)vh | ((u32)vl << 16);
                }
            }
        }
    }
}

// ---------------- decoder stages 2/3: K=128 GEMM from packed planes ----------------
// TBASE: first swizzled tile (8=Wd2, 40=Wd3). ACT 1: relu -> packed; ACT 2: softplus -> out.
template<int TBASE, int ACT>
__global__ __launch_bounds__(256, 2) void dec_stage128(
    const u16* __restrict__ whi, const u16* __restrict__ wlo,
    const u32* __restrict__ inP, const float* __restrict__ bias,
    u32* __restrict__ outP, float* __restrict__ out, int n, int ntiles) {
    __shared__ __align__(16) u16 wbH[32][512], wbL[32][512];   // 64 KB
    const int tid = threadIdx.x;
    const int l = tid & 63, wv = tid >> 6;
    const int lr = l & 15, lg = l >> 4;

    for (int i = tid; i < 32 * 64; i += 256) {
        ((int4*)wbH)[i] = ((const int4*)whi)[TBASE * 64 + i];
        ((int4*)wbL)[i] = ((const int4*)wlo)[TBASE * 64 + i];
    }
    __syncthreads();

    for (int t = blockIdx.x; t < ntiles; t += gridDim.x) {
        const int row0 = t * 64;
        int arow = row0 + wv * 16 + lr; if (arow >= n) arow = n - 1;
        const u32* pP = &inP[(size_t)arow * 128 + lg * 8];
        f4 acc[8];
#pragma unroll
        for (int ct = 0; ct < 8; ++ct) acc[ct] = (f4){0.f, 0.f, 0.f, 0.f};
#pragma unroll
        for (int kt = 0; kt < 4; ++kt) {
            u32 w[8];
            *(uint4*)&w[0] = *(const uint4*)(pP + kt * 32);
            *(uint4*)&w[4] = *(const uint4*)(pP + kt * 32 + 4);
            bf8 aH, aL;
#pragma unroll
            for (int j = 0; j < 8; ++j) {
                ((u16*)&aH)[j] = (u16)(w[j] & 0xffffu);
                ((u16*)&aL)[j] = (u16)(w[j] >> 16);
            }
#pragma unroll
            for (int ct = 0; ct < 8; ++ct) {
                bf8 bH = *(const bf8*)&wbH[kt * 8 + ct][l * 8];
                bf8 bL = *(const bf8*)&wbL[kt * 8 + ct][l * 8];
                acc[ct] = __builtin_amdgcn_mfma_f32_16x16x32_bf16(aH, bH, acc[ct], 0, 0, 0);
                acc[ct] = __builtin_amdgcn_mfma_f32_16x16x32_bf16(aL, bH, acc[ct], 0, 0, 0);
                acc[ct] = __builtin_amdgcn_mfma_f32_16x16x32_bf16(aH, bL, acc[ct], 0, 0, 0);
            }
        }
#pragma unroll
        for (int ct = 0; ct < 8; ++ct) {
            float bv = bias[ct * 16 + lr];
#pragma unroll
            for (int rg = 0; rg < 4; ++rg) {
                int g = row0 + wv * 16 + lg * 4 + rg;
                if (g < n) {
                    float v = acc[ct][rg] + bv;
                    if (ACT == 1) {
                        v = fmaxf(v, 0.f);
                        u16 vh = bfhi(v), vl = bfhi(v - bf2f(vh));
                        outP[(size_t)g * 128 + ct * 16 + lr] = (u32)vh | ((u32)vl << 16);
                    } else {
                        v = fmaxf(v, 0.f) + __logf(1.f + __expf(-fabsf(v)));
                        out[(size_t)g * 170 + 42 + ct * 16 + lr] = v;
                    }
                }
            }
        }
    }
}

// ---------------- launch ----------------

extern "C" void kernel_launch(void* const* d_in, const int* in_sizes, int n_in,
                              void* d_out, int out_size, void* d_ws, size_t ws_size,
                              hipStream_t stream) {
    const float* raw_x = (const float*)d_in[0];
    const int*   ei    = (const int*)d_in[1];
    const float* W1 = (const float*)d_in[2];  const float* b1 = (const float*)d_in[3];
    const float* W2 = (const float*)d_in[4];  const float* b2 = (const float*)d_in[5];
    const float* Wp = (const float*)d_in[6];  const float* bp = (const float*)d_in[7];
    const float* Wd1 = (const float*)d_in[8]; const float* bd1 = (const float*)d_in[9];
    const float* Wd2 = (const float*)d_in[10]; const float* bd2 = (const float*)d_in[11];
    const float* Wd3 = (const float*)d_in[12]; const float* bd3 = (const float*)d_in[13];

    const int n = in_sizes[0] / 128;   // 50000
    const int E = in_sizes[1] / 2;     // 800000
    const int* row = ei;        // source
    const int* col = ei + E;    // target

    float* out = (float*)d_out;

    const int CH   = 8192;
    const int nwg  = (E + CH - 1) / CH;     // 98
    const int nbuk = (n + 63) >> 6;         // 782

    // workspace layout (aligned)
    char* ws = (char*)d_ws;
    auto alloc = [&](size_t bytes) {
        ws = (char*)(((uintptr_t)ws + 255) & ~(uintptr_t)255);
        char* p = ws; ws += bytes; return (void*)p;
    };
    float* dinv   = (float*)alloc((size_t)n * 4);
    int*   rowptr = (int*)alloc((size_t)(n + 4) * 4);
    int*   boff   = (int*)alloc((size_t)(nbuk + 4) * 4);
    int*   bsum   = (int*)alloc((size_t)nbuk * 4);
    int*   M      = (int*)alloc((size_t)nbuk * nwg * 4);
    int*   csrc   = (int*)alloc((size_t)E * 4);
    float* hs1    = (float*)alloc((size_t)n * 64 * 4);   // overlays: ebuf (build), h1P low half (decode)
    float* x1     = (float*)alloc((size_t)n * 64 * 4);   // h1P high half
    float* hs2    = (float*)alloc((size_t)n * 32 * 4);
    u16*   wswHi  = (u16*)alloc((size_t)73 * 512 * 2);
    u16*   wswLo  = (u16*)alloc((size_t)73 * 512 * 2);
    u32*   h2P    = (u32*)alloc((size_t)n * 128 * 4);
    int2*  ebuf   = (int2*)hs1;           // dead before gemm1 writes hs1
    u32*   h1P    = (u32*)hs1;            // spans hs1+x1 (contiguous, dead post-agg2)

    const int BS = 256;
    auto blocks = [](long long work, int bs) { return (unsigned)((work + bs - 1) / bs); };
    const int ntiles = (n + 63) / 64;                // 782

    // ---- graph structure: bucketed counting sort (zero global atomics) ----
    bucket_hist<<<nwg, 256, 0, stream>>>(col, M, E, nbuk, nwg);
    col_scan<<<blocks(nbuk, 256), 256, 0, stream>>>(M, bsum, nbuk, nwg);
    bucket_scan<<<1, 1024, 0, stream>>>(bsum, boff, rowptr, nbuk, n, E);
    bucket_scatter<<<nwg, 256, 0, stream>>>(row, col, M, boff, ebuf, E, nwg);
    bucket_finalize<<<nbuk, 256, 0, stream>>>(ebuf, boff, rowptr, csrc, dinv, n);

    // ---- weight swizzle (independent) ----
    wswz_kernel<<<73, 64, 0, stream>>>(Wd1, Wd2, Wd3, Wp, wswHi, wswLo);

    // ---- GCN layer 1: raw_x[128] -> 64 ----
    gemm_gcn<128, 64><<<blocks(n, 64), 256, 0, stream>>>(raw_x, W1, dinv, hs1, n);
    agg_finalize<64, true><<<blocks((long long)n * 16, BS), BS, 0, stream>>>(
        rowptr, csrc, hs1, dinv, b1, x1, n, 64, 0);

    // ---- GCN layer 2: x1[64] -> 32 ----
    gemm_gcn<64, 32><<<blocks(n, 64), 256, 0, stream>>>(x1, W2, dinv, hs2, n);
    agg_finalize<32, false><<<blocks((long long)n * 8, BS), BS, 0, stream>>>(
        rowptr, csrc, hs2, dinv, b2, out, n, 170, 0);   // emb -> out[:,0:32)
    // hs1/x1 dead from here -> reused as packed h1 plane.

    // ---- decoder: 3 compact looped MFMA kernels (packed h planes) ----
    dec_stage1<<<512, 256, 0, stream>>>(out, wswHi, wswLo, bp, bd1, h1P, out, n, ntiles);
    dec_stage128<8, 1><<<512, 256, 0, stream>>>(wswHi, wswLo, h1P, bd2, h2P, nullptr, n, ntiles);
    dec_stage128<40, 2><<<512, 256, 0, stream>>>(wswHi, wswLo, h2P, bd3, nullptr, out, n, ntiles);
}

// Round 12
// 247.851 us; speedup vs baseline: 1.3802x; 1.1480x over previous
//
#include <hip/hip_runtime.h>
#include <math.h>

typedef unsigned short u16;
typedef unsigned int u32;
typedef __attribute__((ext_vector_type(8))) short bf8;   // 8 bf16 = 4 VGPR
typedef __attribute__((ext_vector_type(4))) float f4;    // 4 f32 acc

__device__ __forceinline__ u16 bfhi(float x) {
    u32 u = __float_as_uint(x);
    u32 r = u + 0x7FFFu + ((u >> 16) & 1u);   // RNE
    return (u16)(r >> 16);
}
__device__ __forceinline__ float bf2f(u16 h) { return __uint_as_float(((u32)h) << 16); }

// ================= graph build: zero-global-atomic bucketed CSR =================
// bucket = col >> 6 (64 nodes per bucket). CH = 8192 edges per workgroup.

__global__ __launch_bounds__(256) void bucket_hist(const int* __restrict__ col,
                                                   int* __restrict__ M, int E, int nbuk, int nwg) {
    __shared__ int h[1024];
    const int tid = threadIdx.x;
    for (int i = tid; i < 1024; i += 256) h[i] = 0;
    __syncthreads();
    int base = blockIdx.x * 8192;
    for (int i = tid; i < 8192; i += 256) {
        int e = base + i;
        if (e < E) atomicAdd(&h[col[e] >> 6], 1);   // LDS atomic
    }
    __syncthreads();
    for (int b = tid; b < nbuk; b += 256) M[b * nwg + blockIdx.x] = h[b];
}

// per-bucket exclusive scan over workgroups (in place), bucket totals -> bsum
__global__ void col_scan(int* __restrict__ M, int* __restrict__ bsum, int nbuk, int nwg) {
    int b = blockIdx.x * blockDim.x + threadIdx.x;
    if (b >= nbuk) return;
    int s = 0;
    for (int w = 0; w < nwg; ++w) { int t = M[b * nwg + w]; M[b * nwg + w] = s; s += t; }
    bsum[b] = s;
}

// single block: exclusive scan of bucket sums -> boff; boff[nbuk]=E; rowptr[n]=E
__global__ void bucket_scan(const int* __restrict__ bsum, int* __restrict__ boff,
                            int* __restrict__ rowptr, int nbuk, int n, int E) {
    __shared__ int sh[1024];
    const int tid = threadIdx.x;
    int v = (tid < nbuk) ? bsum[tid] : 0;
    sh[tid] = v; __syncthreads();
    for (int off = 1; off < 1024; off <<= 1) {
        int x = sh[tid];
        int w = (tid >= off) ? sh[tid - off] : 0;
        __syncthreads();
        sh[tid] = x + w;
        __syncthreads();
    }
    if (tid < nbuk) boff[tid] = sh[tid] - v;
    if (tid == 0) { boff[nbuk] = E; rowptr[n] = E; }
}

// scatter edges into bucket-sorted ebuf (LDS ranks, no global atomics)
__global__ __launch_bounds__(256) void bucket_scatter(const int* __restrict__ row,
                                                      const int* __restrict__ col,
                                                      const int* __restrict__ M,
                                                      const int* __restrict__ boff,
                                                      int2* __restrict__ ebuf, int E, int nwg) {
    __shared__ int h[1024];
    const int tid = threadIdx.x;
    for (int i = tid; i < 1024; i += 256) h[i] = 0;
    __syncthreads();
    int base = blockIdx.x * 8192;
    for (int i = tid; i < 8192; i += 256) {
        int e = base + i;
        if (e < E) {
            int c = col[e], b = c >> 6;
            int rank = atomicAdd(&h[b], 1);  // LDS
            int slot = boff[b] + M[b * nwg + blockIdx.x] + rank;
            ebuf[slot] = make_int2(c, row[e]);
        }
    }
}

// per-bucket: node histogram -> dinv + rowptr + node-sorted csrc (all bucket-local)
__global__ __launch_bounds__(256) void bucket_finalize(const int2* __restrict__ ebuf,
                                                       const int* __restrict__ boff,
                                                       int* __restrict__ rowptr,
                                                       int* __restrict__ csrc,
                                                       float* __restrict__ dinv, int n) {
    __shared__ int h[64];
    __shared__ int curs[64];
    const int b = blockIdx.x, tid = threadIdx.x;
    const int n0 = b << 6;
    const int beg = boff[b], end = boff[b + 1];
    if (tid < 64) h[tid] = 0;
    __syncthreads();
    for (int i = beg + tid; i < end; i += 256) atomicAdd(&h[ebuf[i].x & 63], 1);
    __syncthreads();
    if (tid < 64) {                    // first wave: 64-lane shfl scan
        int cnt = h[tid];
        int v = cnt;
        for (int off = 1; off < 64; off <<= 1) {
            int w = __shfl_up(v, off);
            if (tid >= off) v += w;
        }
        int cursor = beg + v - cnt;    // exclusive
        curs[tid] = cursor;
        int node = n0 + tid;
        if (node < n) {
            rowptr[node] = cursor;
            dinv[node] = rsqrtf((float)(cnt + 1));   // +1 self loop
        }
    }
    __syncthreads();
    for (int i = beg + tid; i < end; i += 256) {
        int2 e = ebuf[i];
        int slot = atomicAdd(&curs[e.x & 63], 1);    // LDS
        csrc[slot] = e.y;
    }
}

// ---------------- CSR gather aggregation + finalize ----------------
template<int F, bool OV>
__global__ void agg_finalize(const int* __restrict__ rowptr, const int* __restrict__ csrc,
                             const float* __restrict__ hs, const float* __restrict__ dinv,
                             const float* __restrict__ b, float* __restrict__ out,
                             int n, int ostride, int col0) {
    constexpr int L = F / 4;                 // lanes per node
    int tid = blockIdx.x * blockDim.x + threadIdx.x;
    int node = tid / L, lane = tid % L;
    if (node >= n) return;
    int f0 = lane * 4;
    int beg = rowptr[node], end = rowptr[node + 1];
    float4 sum = make_float4(0.f, 0.f, 0.f, 0.f);
    for (int j = beg; j < end; ++j) {
        int s = csrc[j];                     // uniform across the L-lane group
        float4 v = *(const float4*)&hs[(size_t)s * F + f0];
        sum.x += v.x; sum.y += v.y; sum.z += v.z; sum.w += v.w;
    }
    float4 self = *(const float4*)&hs[(size_t)node * F + f0];
    float di = dinv[node];
    float r0 = fmaxf(di * (sum.x + self.x) + b[f0 + 0], 0.f);
    float r1 = fmaxf(di * (sum.y + self.y) + b[f0 + 1], 0.f);
    float r2 = fmaxf(di * (sum.z + self.z) + b[f0 + 2], 0.f);
    float r3 = fmaxf(di * (sum.w + self.w) + b[f0 + 3], 0.f);
    float* op = &out[(size_t)node * ostride + col0 + f0];
    if (OV) {
        *(float4*)op = make_float4(r0, r1, r2, r3);
    } else {
        op[0] = r0; op[1] = r1; op[2] = r2; op[3] = r3;
    }
}

// ---------------- GCN dense: out[r,c] = dinv[r] * sum_k x[r,k]*W[k,c] ----------------
template<int K, int OC>
__global__ __launch_bounds__(256) void gemm_gcn(
    const float* __restrict__ x, const float* __restrict__ W,
    const float* __restrict__ dinv, float* __restrict__ outp, int n) {
    constexpr int CG = OC / 8;        // col groups
    constexpr int RG = 256 / CG;      // row groups
    constexpr int ROWS = 64 / RG;     // rows per thread
    __shared__ float xL[64][K + 4];

    const int tid = threadIdx.x;
    const int cg = tid % CG, rg = tid / CG;
    const int c0 = cg * 8, r0 = rg * ROWS;
    const int row0 = blockIdx.x * 64;

#pragma unroll
    for (int i = 0; i < K / 16; ++i) {
        int e = tid + i * 256;
        int r = e / (K / 4), q = e % (K / 4);
        float4 v = make_float4(0.f, 0.f, 0.f, 0.f);
        if (row0 + r < n) v = *(const float4*)&x[(size_t)(row0 + r) * K + q * 4];
        *(float4*)&xL[r][q * 4] = v;
    }
    __syncthreads();

    float acc[ROWS][8];
#pragma unroll
    for (int r = 0; r < ROWS; ++r)
#pragma unroll
        for (int c = 0; c < 8; ++c) acc[r][c] = 0.f;

#pragma unroll 8
    for (int k = 0; k < K; ++k) {
        float4 w0 = *(const float4*)&W[(size_t)k * OC + c0];
        float4 w1 = *(const float4*)&W[(size_t)k * OC + c0 + 4];
        float wv[8] = {w0.x, w0.y, w0.z, w0.w, w1.x, w1.y, w1.z, w1.w};
        float xv[ROWS];
#pragma unroll
        for (int r = 0; r < ROWS; ++r) xv[r] = xL[r0 + r][k];
#pragma unroll
        for (int r = 0; r < ROWS; ++r)
#pragma unroll
            for (int c = 0; c < 8; ++c) acc[r][c] = fmaf(xv[r], wv[c], acc[r][c]);
    }

#pragma unroll
    for (int r = 0; r < ROWS; ++r) {
        int gr = row0 + r0 + r;
        if (gr >= n) continue;
        float di = dinv[gr];
        float* op = &outp[(size_t)gr * OC + c0];
        *(float4*)op = make_float4(acc[r][0] * di, acc[r][1] * di, acc[r][2] * di, acc[r][3] * di);
        *(float4*)(op + 4) = make_float4(acc[r][4] * di, acc[r][5] * di, acc[r][6] * di, acc[r][7] * di);
    }
}

// ---------------- weight pre-swizzle into MFMA B-fragment order ----------------
// B-frag for mfma_f32_16x16x32_bf16: lane l holds B[kt*32 + (l>>4)*8 + j][ct*16 + (l&15)], j=0..7
// tiles: 0..7 Wd1(32x128), 8..39 Wd2(128x128), 40..71 Wd3(128x128), 72 Wp(32x10 pad16)
__global__ void wswz_kernel(const float* __restrict__ Wd1, const float* __restrict__ Wd2,
                            const float* __restrict__ Wd3, const float* __restrict__ Wp,
                            u16* __restrict__ whi, u16* __restrict__ wlo) {
    int t = blockIdx.x, l = threadIdx.x;   // 73 blocks x 64 threads
    const float* W; int C, kt, ct;
    if (t < 8)       { W = Wd1; C = 128; kt = 0;           ct = t; }
    else if (t < 40) { W = Wd2; C = 128; kt = (t - 8) >> 3; ct = (t - 8) & 7; }
    else if (t < 72) { W = Wd3; C = 128; kt = (t - 40) >> 3; ct = (t - 40) & 7; }
    else             { W = Wp;  C = 10;  kt = 0;           ct = 0; }
    int kbase = kt * 32 + (l >> 4) * 8;
    int c = ct * 16 + (l & 15);
    size_t base = (size_t)t * 512 + (size_t)l * 8;
#pragma unroll
    for (int j = 0; j < 8; ++j) {
        float v = (c < C) ? W[(size_t)(kbase + j) * C + c] : 0.f;
        u16 h = bfhi(v);
        whi[base + j] = (u16)h;
        wlo[base + j] = bfhi(v - bf2f(h));
    }
}

// ---------------- fully-fused MFMA decoder ----------------
// ALL 73 weight tiles resident in LDS (146 KB) for the whole kernel; grid-stride
// over 64-row tiles; h1/h2 never touch global — handoff C-layout -> A-layout via
// a small padded LDS scratch per 32-col slice (wave-local rows, no barriers).
// LDS total = 146 KB + 9 KB = 155 KB -> 1 block/CU, 4 waves.
__global__ __launch_bounds__(256, 1) void dec_fused(
    const float* __restrict__ obuf,
    const u16* __restrict__ whi, const u16* __restrict__ wlo,
    const float* __restrict__ bp, const float* __restrict__ bd1,
    const float* __restrict__ bd2, const float* __restrict__ bd3,
    float* __restrict__ out, int n, int ntiles) {
    __shared__ __align__(16) u16 wbH[73][512];   // 74752 B
    __shared__ __align__(16) u16 wbL[73][512];   // 74752 B
    __shared__ __align__(16) u32 scr[64][36];    // 9216 B (row pad 36: 16B-aligned rows, spread banks)

    const int tid = threadIdx.x;
    const int l = tid & 63, wv = tid >> 6;
    const int lr = l & 15, lg = l >> 4;
    const int wrow = wv * 16;

    // stage all weights once per block
    for (int i = tid; i < 73 * 64; i += 256) {
        ((int4*)wbH)[i] = ((const int4*)whi)[i];
        ((int4*)wbL)[i] = ((const int4*)wlo)[i];
    }
    __syncthreads();

    for (int t = blockIdx.x; t < ntiles; t += gridDim.x) {
        const int row0 = t * 64;
        int arow = row0 + wrow + lr; if (arow >= n) arow = n - 1;   // clamp; stores guarded

        // ---- A-frag from emb (out[:,0:32)) ----
        const float* src = &obuf[(size_t)arow * 170 + lg * 8];
        bf8 aH, aL;
#pragma unroll
        for (int i = 0; i < 8; i += 2) {
            float2 v = *(const float2*)(src + i);
            u16 h0 = bfhi(v.x), h1 = bfhi(v.y);
            ((u16*)&aH)[i] = h0;     ((u16*)&aH)[i + 1] = h1;
            ((u16*)&aL)[i] = bfhi(v.x - bf2f(h0));
            ((u16*)&aL)[i + 1] = bfhi(v.y - bf2f(h1));
        }

        // ---- stage 1: h1 = emb @ Wd1 (tiles 0..7), head = emb @ Wp (tile 72) ----
        f4 acc1[8];
#pragma unroll
        for (int ct = 0; ct < 8; ++ct) {
            bf8 bH = *(const bf8*)&wbH[ct][l * 8];
            bf8 bL = *(const bf8*)&wbL[ct][l * 8];
            f4 a = (f4){0.f, 0.f, 0.f, 0.f};
            a = __builtin_amdgcn_mfma_f32_16x16x32_bf16(aH, bH, a, 0, 0, 0);
            a = __builtin_amdgcn_mfma_f32_16x16x32_bf16(aL, bH, a, 0, 0, 0);
            a = __builtin_amdgcn_mfma_f32_16x16x32_bf16(aH, bL, a, 0, 0, 0);
            acc1[ct] = a;
        }
        {   // head
            bf8 pH = *(const bf8*)&wbH[72][l * 8];
            bf8 pL = *(const bf8*)&wbL[72][l * 8];
            f4 p = (f4){0.f, 0.f, 0.f, 0.f};
            p = __builtin_amdgcn_mfma_f32_16x16x32_bf16(aH, pH, p, 0, 0, 0);
            p = __builtin_amdgcn_mfma_f32_16x16x32_bf16(aL, pH, p, 0, 0, 0);
            p = __builtin_amdgcn_mfma_f32_16x16x32_bf16(aH, pL, p, 0, 0, 0);
            if (lr < 10) {
                float bpv = bp[lr];
#pragma unroll
                for (int rg = 0; rg < 4; ++rg) {
                    int g = row0 + wrow + lg * 4 + rg;
                    if (g < n) out[(size_t)g * 170 + 32 + lr] = p[rg] + bpv;
                }
            }
        }

        // ---- stage 2: h2 = relu(h1+bd1) @ Wd2 (tiles 8..39), handoff via scr per kt ----
        f4 acc2[8];
#pragma unroll
        for (int ct = 0; ct < 8; ++ct) acc2[ct] = (f4){0.f, 0.f, 0.f, 0.f};
#pragma unroll
        for (int kt = 0; kt < 4; ++kt) {
#pragma unroll
            for (int cc = 0; cc < 2; ++cc) {
                int ct = kt * 2 + cc;
                float bv = bd1[ct * 16 + lr];
#pragma unroll
                for (int rg = 0; rg < 4; ++rg) {
                    float v = fmaxf(acc1[ct][rg] + bv, 0.f);
                    u16 vh = bfhi(v), vl = bfhi(v - bf2f(vh));
                    scr[wrow + lg * 4 + rg][cc * 16 + lr] = (u32)vh | ((u32)vl << 16);
                }
            }
            u32 w[8];
            *(uint4*)&w[0] = *(const uint4*)&scr[wrow + lr][lg * 8];
            *(uint4*)&w[4] = *(const uint4*)&scr[wrow + lr][lg * 8 + 4];
            bf8 a2H, a2L;
#pragma unroll
            for (int j = 0; j < 8; ++j) {
                ((u16*)&a2H)[j] = (u16)(w[j] & 0xffffu);
                ((u16*)&a2L)[j] = (u16)(w[j] >> 16);
            }
#pragma unroll
            for (int ct = 0; ct < 8; ++ct) {
                bf8 bH = *(const bf8*)&wbH[8 + kt * 8 + ct][l * 8];
                bf8 bL = *(const bf8*)&wbL[8 + kt * 8 + ct][l * 8];
                acc2[ct] = __builtin_amdgcn_mfma_f32_16x16x32_bf16(a2H, bH, acc2[ct], 0, 0, 0);
                acc2[ct] = __builtin_amdgcn_mfma_f32_16x16x32_bf16(a2L, bH, acc2[ct], 0, 0, 0);
                acc2[ct] = __builtin_amdgcn_mfma_f32_16x16x32_bf16(a2H, bL, acc2[ct], 0, 0, 0);
            }
        }

        // ---- stage 3: dec = relu(h2+bd2) @ Wd3 (tiles 40..71) ----
        f4 acc3[8];
#pragma unroll
        for (int ct = 0; ct < 8; ++ct) acc3[ct] = (f4){0.f, 0.f, 0.f, 0.f};
#pragma unroll
        for (int kt = 0; kt < 4; ++kt) {
#pragma unroll
            for (int cc = 0; cc < 2; ++cc) {
                int ct = kt * 2 + cc;
                float bv = bd2[ct * 16 + lr];
#pragma unroll
                for (int rg = 0; rg < 4; ++rg) {
                    float v = fmaxf(acc2[ct][rg] + bv, 0.f);
                    u16 vh = bfhi(v), vl = bfhi(v - bf2f(vh));
                    scr[wrow + lg * 4 + rg][cc * 16 + lr] = (u32)vh | ((u32)vl << 16);
                }
            }
            u32 w[8];
            *(uint4*)&w[0] = *(const uint4*)&scr[wrow + lr][lg * 8];
            *(uint4*)&w[4] = *(const uint4*)&scr[wrow + lr][lg * 8 + 4];
            bf8 a3H, a3L;
#pragma unroll
            for (int j = 0; j < 8; ++j) {
                ((u16*)&a3H)[j] = (u16)(w[j] & 0xffffu);
                ((u16*)&a3L)[j] = (u16)(w[j] >> 16);
            }
#pragma unroll
            for (int ct = 0; ct < 8; ++ct) {
                bf8 bH = *(const bf8*)&wbH[40 + kt * 8 + ct][l * 8];
                bf8 bL = *(const bf8*)&wbL[40 + kt * 8 + ct][l * 8];
                acc3[ct] = __builtin_amdgcn_mfma_f32_16x16x32_bf16(a3H, bH, acc3[ct], 0, 0, 0);
                acc3[ct] = __builtin_amdgcn_mfma_f32_16x16x32_bf16(a3L, bH, acc3[ct], 0, 0, 0);
                acc3[ct] = __builtin_amdgcn_mfma_f32_16x16x32_bf16(a3H, bL, acc3[ct], 0, 0, 0);
            }
        }

        // ---- epilogue: softplus -> out[:,42:170) ----
#pragma unroll
        for (int ct = 0; ct < 8; ++ct) {
            float bv = bd3[ct * 16 + lr];
#pragma unroll
            for (int rg = 0; rg < 4; ++rg) {
                int g = row0 + wrow + lg * 4 + rg;
                if (g < n) {
                    float v = acc3[ct][rg] + bv;
                    v = fmaxf(v, 0.f) + __logf(1.f + __expf(-fabsf(v)));
                    out[(size_t)g * 170 + 42 + ct * 16 + lr] = v;
                }
            }
        }
    }
}

// ---------------- launch ----------------

extern "C" void kernel_launch(void* const* d_in, const int* in_sizes, int n_in,
                              void* d_out, int out_size, void* d_ws, size_t ws_size,
                              hipStream_t stream) {
    const float* raw_x = (const float*)d_in[0];
    const int*   ei    = (const int*)d_in[1];
    const float* W1 = (const float*)d_in[2];  const float* b1 = (const float*)d_in[3];
    const float* W2 = (const float*)d_in[4];  const float* b2 = (const float*)d_in[5];
    const float* Wp = (const float*)d_in[6];  const float* bp = (const float*)d_in[7];
    const float* Wd1 = (const float*)d_in[8]; const float* bd1 = (const float*)d_in[9];
    const float* Wd2 = (const float*)d_in[10]; const float* bd2 = (const float*)d_in[11];
    const float* Wd3 = (const float*)d_in[12]; const float* bd3 = (const float*)d_in[13];

    const int n = in_sizes[0] / 128;   // 50000
    const int E = in_sizes[1] / 2;     // 800000
    const int* row = ei;        // source
    const int* col = ei + E;    // target

    float* out = (float*)d_out;

    const int CH   = 8192;
    const int nwg  = (E + CH - 1) / CH;     // 98
    const int nbuk = (n + 63) >> 6;         // 782

    // workspace layout (aligned)
    char* ws = (char*)d_ws;
    auto alloc = [&](size_t bytes) {
        ws = (char*)(((uintptr_t)ws + 255) & ~(uintptr_t)255);
        char* p = ws; ws += bytes; return (void*)p;
    };
    float* dinv   = (float*)alloc((size_t)n * 4);
    int*   rowptr = (int*)alloc((size_t)(n + 4) * 4);
    int*   boff   = (int*)alloc((size_t)(nbuk + 4) * 4);
    int*   bsum   = (int*)alloc((size_t)nbuk * 4);
    int*   M      = (int*)alloc((size_t)nbuk * nwg * 4);
    int*   csrc   = (int*)alloc((size_t)E * 4);
    float* hs1    = (float*)alloc((size_t)n * 64 * 4);   // overlays ebuf (build)
    float* x1     = (float*)alloc((size_t)n * 64 * 4);
    float* hs2    = (float*)alloc((size_t)n * 32 * 4);
    u16*   wswHi  = (u16*)alloc((size_t)73 * 512 * 2);
    u16*   wswLo  = (u16*)alloc((size_t)73 * 512 * 2);
    int2*  ebuf   = (int2*)hs1;           // dead before gemm1 writes hs1

    const int BS = 256;
    auto blocks = [](long long work, int bs) { return (unsigned)((work + bs - 1) / bs); };
    const int ntiles = (n + 63) / 64;                // 782

    // ---- graph structure: bucketed counting sort (zero global atomics) ----
    bucket_hist<<<nwg, 256, 0, stream>>>(col, M, E, nbuk, nwg);
    col_scan<<<blocks(nbuk, 256), 256, 0, stream>>>(M, bsum, nbuk, nwg);
    bucket_scan<<<1, 1024, 0, stream>>>(bsum, boff, rowptr, nbuk, n, E);
    bucket_scatter<<<nwg, 256, 0, stream>>>(row, col, M, boff, ebuf, E, nwg);
    bucket_finalize<<<nbuk, 256, 0, stream>>>(ebuf, boff, rowptr, csrc, dinv, n);

    // ---- weight swizzle (independent) ----
    wswz_kernel<<<73, 64, 0, stream>>>(Wd1, Wd2, Wd3, Wp, wswHi, wswLo);

    // ---- GCN layer 1: raw_x[128] -> 64 ----
    gemm_gcn<128, 64><<<blocks(n, 64), 256, 0, stream>>>(raw_x, W1, dinv, hs1, n);
    agg_finalize<64, true><<<blocks((long long)n * 16, BS), BS, 0, stream>>>(
        rowptr, csrc, hs1, dinv, b1, x1, n, 64, 0);

    // ---- GCN layer 2: x1[64] -> 32 ----
    gemm_gcn<64, 32><<<blocks(n, 64), 256, 0, stream>>>(x1, W2, dinv, hs2, n);
    agg_finalize<32, false><<<blocks((long long)n * 8, BS), BS, 0, stream>>>(
        rowptr, csrc, hs2, dinv, b2, out, n, 170, 0);   // emb -> out[:,0:32)

    // ---- fully-fused decoder (weights resident in LDS) ----
    dec_fused<<<256, 256, 0, stream>>>(out, wswHi, wswLo, bp, bd1, bd2, bd3, out, n, ntiles);
}

// Round 13
// 244.609 us; speedup vs baseline: 1.3985x; 1.0133x over previous
//
#include <hip/hip_runtime.h>
#include <math.h>

typedef unsigned short u16;
typedef unsigned int u32;
typedef __attribute__((ext_vector_type(8))) short bf8;   // 8 bf16 = 4 VGPR
typedef __attribute__((ext_vector_type(4))) float f4;    // 4 f32 acc

__device__ __forceinline__ u16 bfhi(float x) {
    u32 u = __float_as_uint(x);
    u32 r = u + 0x7FFFu + ((u >> 16) & 1u);   // RNE
    return (u16)(r >> 16);
}
__device__ __forceinline__ float bf2f(u16 h) { return __uint_as_float(((u32)h) << 16); }

// ================= graph build: zero-global-atomic bucketed CSR =================
// bucket = col >> 6 (64 nodes per bucket). CH = 8192 edges per workgroup.

__global__ __launch_bounds__(256) void bucket_hist(const int* __restrict__ col,
                                                   int* __restrict__ M, int E, int nbuk, int nwg) {
    __shared__ int h[1024];
    const int tid = threadIdx.x;
    for (int i = tid; i < 1024; i += 256) h[i] = 0;
    __syncthreads();
    int base = blockIdx.x * 8192;
    for (int i = tid; i < 8192; i += 256) {
        int e = base + i;
        if (e < E) atomicAdd(&h[col[e] >> 6], 1);   // LDS atomic
    }
    __syncthreads();
    for (int b = tid; b < nbuk; b += 256) M[b * nwg + blockIdx.x] = h[b];
}

// per-bucket exclusive scan over workgroups (in place), bucket totals -> bsum
__global__ void col_scan(int* __restrict__ M, int* __restrict__ bsum, int nbuk, int nwg) {
    int b = blockIdx.x * blockDim.x + threadIdx.x;
    if (b >= nbuk) return;
    int s = 0;
    for (int w = 0; w < nwg; ++w) { int t = M[b * nwg + w]; M[b * nwg + w] = s; s += t; }
    bsum[b] = s;
}

// single block: exclusive scan of bucket sums -> boff; boff[nbuk]=E; rowptr[n]=E
__global__ void bucket_scan(const int* __restrict__ bsum, int* __restrict__ boff,
                            int* __restrict__ rowptr, int nbuk, int n, int E) {
    __shared__ int sh[1024];
    const int tid = threadIdx.x;
    int v = (tid < nbuk) ? bsum[tid] : 0;
    sh[tid] = v; __syncthreads();
    for (int off = 1; off < 1024; off <<= 1) {
        int x = sh[tid];
        int w = (tid >= off) ? sh[tid - off] : 0;
        __syncthreads();
        sh[tid] = x + w;
        __syncthreads();
    }
    if (tid < nbuk) boff[tid] = sh[tid] - v;
    if (tid == 0) { boff[nbuk] = E; rowptr[n] = E; }
}

// scatter edges into bucket-sorted ebuf (LDS ranks, no global atomics)
__global__ __launch_bounds__(256) void bucket_scatter(const int* __restrict__ row,
                                                      const int* __restrict__ col,
                                                      const int* __restrict__ M,
                                                      const int* __restrict__ boff,
                                                      int2* __restrict__ ebuf, int E, int nwg) {
    __shared__ int h[1024];
    const int tid = threadIdx.x;
    for (int i = tid; i < 1024; i += 256) h[i] = 0;
    __syncthreads();
    int base = blockIdx.x * 8192;
    for (int i = tid; i < 8192; i += 256) {
        int e = base + i;
        if (e < E) {
            int c = col[e], b = c >> 6;
            int rank = atomicAdd(&h[b], 1);  // LDS
            int slot = boff[b] + M[b * nwg + blockIdx.x] + rank;
            ebuf[slot] = make_int2(c, row[e]);
        }
    }
}

// per-bucket: node histogram -> dinv + rowptr + node-sorted csrc (all bucket-local)
__global__ __launch_bounds__(256) void bucket_finalize(const int2* __restrict__ ebuf,
                                                       const int* __restrict__ boff,
                                                       int* __restrict__ rowptr,
                                                       int* __restrict__ csrc,
                                                       float* __restrict__ dinv, int n) {
    __shared__ int h[64];
    __shared__ int curs[64];
    const int b = blockIdx.x, tid = threadIdx.x;
    const int n0 = b << 6;
    const int beg = boff[b], end = boff[b + 1];
    if (tid < 64) h[tid] = 0;
    __syncthreads();
    for (int i = beg + tid; i < end; i += 256) atomicAdd(&h[ebuf[i].x & 63], 1);
    __syncthreads();
    if (tid < 64) {                    // first wave: 64-lane shfl scan
        int cnt = h[tid];
        int v = cnt;
        for (int off = 1; off < 64; off <<= 1) {
            int w = __shfl_up(v, off);
            if (tid >= off) v += w;
        }
        int cursor = beg + v - cnt;    // exclusive
        curs[tid] = cursor;
        int node = n0 + tid;
        if (node < n) {
            rowptr[node] = cursor;
            dinv[node] = rsqrtf((float)(cnt + 1));   // +1 self loop
        }
    }
    __syncthreads();
    for (int i = beg + tid; i < end; i += 256) {
        int2 e = ebuf[i];
        int slot = atomicAdd(&curs[e.x & 63], 1);    // LDS
        csrc[slot] = e.y;
    }
}

// ---------------- CSR gather aggregation + finalize ----------------
template<int F, bool OV>
__global__ void agg_finalize(const int* __restrict__ rowptr, const int* __restrict__ csrc,
                             const float* __restrict__ hs, const float* __restrict__ dinv,
                             const float* __restrict__ b, float* __restrict__ out,
                             int n, int ostride, int col0) {
    constexpr int L = F / 4;                 // lanes per node
    int tid = blockIdx.x * blockDim.x + threadIdx.x;
    int node = tid / L, lane = tid % L;
    if (node >= n) return;
    int f0 = lane * 4;
    int beg = rowptr[node], end = rowptr[node + 1];
    float4 sum = make_float4(0.f, 0.f, 0.f, 0.f);
    for (int j = beg; j < end; ++j) {
        int s = csrc[j];                     // uniform across the L-lane group
        float4 v = *(const float4*)&hs[(size_t)s * F + f0];
        sum.x += v.x; sum.y += v.y; sum.z += v.z; sum.w += v.w;
    }
    float4 self = *(const float4*)&hs[(size_t)node * F + f0];
    float di = dinv[node];
    float r0 = fmaxf(di * (sum.x + self.x) + b[f0 + 0], 0.f);
    float r1 = fmaxf(di * (sum.y + self.y) + b[f0 + 1], 0.f);
    float r2 = fmaxf(di * (sum.z + self.z) + b[f0 + 2], 0.f);
    float r3 = fmaxf(di * (sum.w + self.w) + b[f0 + 3], 0.f);
    float* op = &out[(size_t)node * ostride + col0 + f0];
    if (OV) {
        *(float4*)op = make_float4(r0, r1, r2, r3);
    } else {
        op[0] = r0; op[1] = r1; op[2] = r2; op[3] = r3;
    }
}

// ---------------- GCN dense: out[r,c] = dinv[r] * sum_k x[r,k]*W[k,c] ----------------
template<int K, int OC>
__global__ __launch_bounds__(256) void gemm_gcn(
    const float* __restrict__ x, const float* __restrict__ W,
    const float* __restrict__ dinv, float* __restrict__ outp, int n) {
    constexpr int CG = OC / 8;        // col groups
    constexpr int RG = 256 / CG;      // row groups
    constexpr int ROWS = 64 / RG;     // rows per thread
    __shared__ float xL[64][K + 4];

    const int tid = threadIdx.x;
    const int cg = tid % CG, rg = tid / CG;
    const int c0 = cg * 8, r0 = rg * ROWS;
    const int row0 = blockIdx.x * 64;

#pragma unroll
    for (int i = 0; i < K / 16; ++i) {
        int e = tid + i * 256;
        int r = e / (K / 4), q = e % (K / 4);
        float4 v = make_float4(0.f, 0.f, 0.f, 0.f);
        if (row0 + r < n) v = *(const float4*)&x[(size_t)(row0 + r) * K + q * 4];
        *(float4*)&xL[r][q * 4] = v;
    }
    __syncthreads();

    float acc[ROWS][8];
#pragma unroll
    for (int r = 0; r < ROWS; ++r)
#pragma unroll
        for (int c = 0; c < 8; ++c) acc[r][c] = 0.f;

#pragma unroll 8
    for (int k = 0; k < K; ++k) {
        float4 w0 = *(const float4*)&W[(size_t)k * OC + c0];
        float4 w1 = *(const float4*)&W[(size_t)k * OC + c0 + 4];
        float wv[8] = {w0.x, w0.y, w0.z, w0.w, w1.x, w1.y, w1.z, w1.w};
        float xv[ROWS];
#pragma unroll
        for (int r = 0; r < ROWS; ++r) xv[r] = xL[r0 + r][k];
#pragma unroll
        for (int r = 0; r < ROWS; ++r)
#pragma unroll
            for (int c = 0; c < 8; ++c) acc[r][c] = fmaf(xv[r], wv[c], acc[r][c]);
    }

#pragma unroll
    for (int r = 0; r < ROWS; ++r) {
        int gr = row0 + r0 + r;
        if (gr >= n) continue;
        float di = dinv[gr];
        float* op = &outp[(size_t)gr * OC + c0];
        *(float4*)op = make_float4(acc[r][0] * di, acc[r][1] * di, acc[r][2] * di, acc[r][3] * di);
        *(float4*)(op + 4) = make_float4(acc[r][4] * di, acc[r][5] * di, acc[r][6] * di, acc[r][7] * di);
    }
}

// ---------------- weight pre-swizzle into MFMA B-fragment order ----------------
// B-frag for mfma_f32_16x16x32_bf16: lane l holds B[kt*32 + (l>>4)*8 + j][ct*16 + (l&15)], j=0..7
// tiles: 0..7 Wd1(32x128), 8..39 Wd2(128x128), 40..71 Wd3(128x128), 72 Wp(32x10 pad16)
__global__ void wswz_kernel(const float* __restrict__ Wd1, const float* __restrict__ Wd2,
                            const float* __restrict__ Wd3, const float* __restrict__ Wp,
                            u16* __restrict__ whi, u16* __restrict__ wlo) {
    int t = blockIdx.x, l = threadIdx.x;   // 73 blocks x 64 threads
    const float* W; int C, kt, ct;
    if (t < 8)       { W = Wd1; C = 128; kt = 0;           ct = t; }
    else if (t < 40) { W = Wd2; C = 128; kt = (t - 8) >> 3; ct = (t - 8) & 7; }
    else if (t < 72) { W = Wd3; C = 128; kt = (t - 40) >> 3; ct = (t - 40) & 7; }
    else             { W = Wp;  C = 10;  kt = 0;           ct = 0; }
    int kbase = kt * 32 + (l >> 4) * 8;
    int c = ct * 16 + (l & 15);
    size_t base = (size_t)t * 512 + (size_t)l * 8;
#pragma unroll
    for (int j = 0; j < 8; ++j) {
        float v = (c < C) ? W[(size_t)(kbase + j) * C + c] : 0.f;
        u16 h = bfhi(v);
        whi[base + j] = (u16)h;
        wlo[base + j] = bfhi(v - bf2f(h));
    }
}

// ---------------- fully-fused MFMA decoder, 2-tile interleave ----------------
// ALL 73 weight tiles resident in LDS; each iteration processes tiles t and
// t+half with fully-unrolled [2]-indexed state: two independent MFMA/handoff
// chains interleave (hides scr ds latency at 1 wave/SIMD), and every B-frag
// LDS read is shared by both tiles (halves LDS weight BW per tile).
// scr WAR across tiles is safe: per-wave DS ops execute in order and the
// compiler preserves must-alias ordering. LDS = 146 + 9 KB -> 1 block/CU.
__global__ __launch_bounds__(256, 1) void dec_fused(
    const float* __restrict__ obuf,
    const u16* __restrict__ whi, const u16* __restrict__ wlo,
    const float* __restrict__ bp, const float* __restrict__ bd1,
    const float* __restrict__ bd2, const float* __restrict__ bd3,
    float* __restrict__ out, int n, int ntiles) {
    __shared__ __align__(16) u16 wbH[73][512];   // 74752 B
    __shared__ __align__(16) u16 wbL[73][512];   // 74752 B
    __shared__ __align__(16) u32 scr[64][36];    // 9216 B

    const int tid = threadIdx.x;
    const int l = tid & 63, wv = tid >> 6;
    const int lr = l & 15, lg = l >> 4;
    const int wrow = wv * 16;
    const int half = (ntiles + 1) >> 1;

    // stage all weights once per block
    for (int i = tid; i < 73 * 64; i += 256) {
        ((int4*)wbH)[i] = ((const int4*)whi)[i];
        ((int4*)wbL)[i] = ((const int4*)wlo)[i];
    }
    __syncthreads();

    for (int t0 = blockIdx.x; t0 < half; t0 += gridDim.x) {
        int row0[2] = {t0 * 64, (t0 + half) * 64};   // tile 2 may exceed n: loads clamp, stores guard

        // ---- A-frags from emb (out[:,0:32)) for both tiles ----
        bf8 aH[2], aL[2];
#pragma unroll
        for (int u = 0; u < 2; ++u) {
            int arow = row0[u] + wrow + lr; if (arow >= n) arow = n - 1;
            const float* src = &obuf[(size_t)arow * 170 + lg * 8];
#pragma unroll
            for (int i = 0; i < 8; i += 2) {
                float2 v = *(const float2*)(src + i);
                u16 h0 = bfhi(v.x), h1 = bfhi(v.y);
                ((u16*)&aH[u])[i] = h0;     ((u16*)&aH[u])[i + 1] = h1;
                ((u16*)&aL[u])[i] = bfhi(v.x - bf2f(h0));
                ((u16*)&aL[u])[i + 1] = bfhi(v.y - bf2f(h1));
            }
        }

        // ---- stage 1: h1 = emb @ Wd1 (tiles 0..7) + head (tile 72), shared B-frags ----
        f4 acc1[2][8];
#pragma unroll
        for (int ct = 0; ct < 8; ++ct) {
            bf8 bH = *(const bf8*)&wbH[ct][l * 8];
            bf8 bL = *(const bf8*)&wbL[ct][l * 8];
#pragma unroll
            for (int u = 0; u < 2; ++u) {
                f4 a = (f4){0.f, 0.f, 0.f, 0.f};
                a = __builtin_amdgcn_mfma_f32_16x16x32_bf16(aH[u], bH, a, 0, 0, 0);
                a = __builtin_amdgcn_mfma_f32_16x16x32_bf16(aL[u], bH, a, 0, 0, 0);
                a = __builtin_amdgcn_mfma_f32_16x16x32_bf16(aH[u], bL, a, 0, 0, 0);
                acc1[u][ct] = a;
            }
        }
        {   // head
            bf8 pH = *(const bf8*)&wbH[72][l * 8];
            bf8 pL = *(const bf8*)&wbL[72][l * 8];
#pragma unroll
            for (int u = 0; u < 2; ++u) {
                f4 p = (f4){0.f, 0.f, 0.f, 0.f};
                p = __builtin_amdgcn_mfma_f32_16x16x32_bf16(aH[u], pH, p, 0, 0, 0);
                p = __builtin_amdgcn_mfma_f32_16x16x32_bf16(aL[u], pH, p, 0, 0, 0);
                p = __builtin_amdgcn_mfma_f32_16x16x32_bf16(aH[u], pL, p, 0, 0, 0);
                if (lr < 10) {
                    float bpv = bp[lr];
#pragma unroll
                    for (int rg = 0; rg < 4; ++rg) {
                        int g = row0[u] + wrow + lg * 4 + rg;
                        if (g < n) out[(size_t)g * 170 + 32 + lr] = p[rg] + bpv;
                    }
                }
            }
        }

        // ---- stage 2: h2 = relu(h1+bd1) @ Wd2 (tiles 8..39) ----
        f4 acc2[2][8];
#pragma unroll
        for (int u = 0; u < 2; ++u)
#pragma unroll
            for (int ct = 0; ct < 8; ++ct) acc2[u][ct] = (f4){0.f, 0.f, 0.f, 0.f};
#pragma unroll
        for (int kt = 0; kt < 4; ++kt) {
            bf8 a2H[2], a2L[2];
#pragma unroll
            for (int u = 0; u < 2; ++u) {    // u=1 write follows u=0 read in program order (DS in-order)
#pragma unroll
                for (int cc = 0; cc < 2; ++cc) {
                    int ct = kt * 2 + cc;
                    float bv = bd1[ct * 16 + lr];
#pragma unroll
                    for (int rg = 0; rg < 4; ++rg) {
                        float v = fmaxf(acc1[u][ct][rg] + bv, 0.f);
                        u16 vh = bfhi(v), vl = bfhi(v - bf2f(vh));
                        scr[wrow + lg * 4 + rg][cc * 16 + lr] = (u32)vh | ((u32)vl << 16);
                    }
                }
                u32 w[8];
                *(uint4*)&w[0] = *(const uint4*)&scr[wrow + lr][lg * 8];
                *(uint4*)&w[4] = *(const uint4*)&scr[wrow + lr][lg * 8 + 4];
#pragma unroll
                for (int j = 0; j < 8; ++j) {
                    ((u16*)&a2H[u])[j] = (u16)(w[j] & 0xffffu);
                    ((u16*)&a2L[u])[j] = (u16)(w[j] >> 16);
                }
            }
#pragma unroll
            for (int ct = 0; ct < 8; ++ct) {
                bf8 bH = *(const bf8*)&wbH[8 + kt * 8 + ct][l * 8];
                bf8 bL = *(const bf8*)&wbL[8 + kt * 8 + ct][l * 8];
#pragma unroll
                for (int u = 0; u < 2; ++u) {
                    acc2[u][ct] = __builtin_amdgcn_mfma_f32_16x16x32_bf16(a2H[u], bH, acc2[u][ct], 0, 0, 0);
                    acc2[u][ct] = __builtin_amdgcn_mfma_f32_16x16x32_bf16(a2L[u], bH, acc2[u][ct], 0, 0, 0);
                    acc2[u][ct] = __builtin_amdgcn_mfma_f32_16x16x32_bf16(a2H[u], bL, acc2[u][ct], 0, 0, 0);
                }
            }
        }

        // ---- stage 3: dec = relu(h2+bd2) @ Wd3 (tiles 40..71) ----
        f4 acc3[2][8];
#pragma unroll
        for (int u = 0; u < 2; ++u)
#pragma unroll
            for (int ct = 0; ct < 8; ++ct) acc3[u][ct] = (f4){0.f, 0.f, 0.f, 0.f};
#pragma unroll
        for (int kt = 0; kt < 4; ++kt) {
            bf8 a3H[2], a3L[2];
#pragma unroll
            for (int u = 0; u < 2; ++u) {
#pragma unroll
                for (int cc = 0; cc < 2; ++cc) {
                    int ct = kt * 2 + cc;
                    float bv = bd2[ct * 16 + lr];
#pragma unroll
                    for (int rg = 0; rg < 4; ++rg) {
                        float v = fmaxf(acc2[u][ct][rg] + bv, 0.f);
                        u16 vh = bfhi(v), vl = bfhi(v - bf2f(vh));
                        scr[wrow + lg * 4 + rg][cc * 16 + lr] = (u32)vh | ((u32)vl << 16);
                    }
                }
                u32 w[8];
                *(uint4*)&w[0] = *(const uint4*)&scr[wrow + lr][lg * 8];
                *(uint4*)&w[4] = *(const uint4*)&scr[wrow + lr][lg * 8 + 4];
#pragma unroll
                for (int j = 0; j < 8; ++j) {
                    ((u16*)&a3H[u])[j] = (u16)(w[j] & 0xffffu);
                    ((u16*)&a3L[u])[j] = (u16)(w[j] >> 16);
                }
            }
#pragma unroll
            for (int ct = 0; ct < 8; ++ct) {
                bf8 bH = *(const bf8*)&wbH[40 + kt * 8 + ct][l * 8];
                bf8 bL = *(const bf8*)&wbL[40 + kt * 8 + ct][l * 8];
#pragma unroll
                for (int u = 0; u < 2; ++u) {
                    acc3[u][ct] = __builtin_amdgcn_mfma_f32_16x16x32_bf16(a3H[u], bH, acc3[u][ct], 0, 0, 0);
                    acc3[u][ct] = __builtin_amdgcn_mfma_f32_16x16x32_bf16(a3L[u], bH, acc3[u][ct], 0, 0, 0);
                    acc3[u][ct] = __builtin_amdgcn_mfma_f32_16x16x32_bf16(a3H[u], bL, acc3[u][ct], 0, 0, 0);
                }
            }
        }

        // ---- epilogue: softplus -> out[:,42:170) ----
#pragma unroll
        for (int u = 0; u < 2; ++u) {
#pragma unroll
            for (int ct = 0; ct < 8; ++ct) {
                float bv = bd3[ct * 16 + lr];
#pragma unroll
                for (int rg = 0; rg < 4; ++rg) {
                    int g = row0[u] + wrow + lg * 4 + rg;
                    if (g < n) {
                        float v = acc3[u][ct][rg] + bv;
                        v = fmaxf(v, 0.f) + __logf(1.f + __expf(-fabsf(v)));
                        out[(size_t)g * 170 + 42 + ct * 16 + lr] = v;
                    }
                }
            }
        }
    }
}

// ---------------- launch ----------------

extern "C" void kernel_launch(void* const* d_in, const int* in_sizes, int n_in,
                              void* d_out, int out_size, void* d_ws, size_t ws_size,
                              hipStream_t stream) {
    const float* raw_x = (const float*)d_in[0];
    const int*   ei    = (const int*)d_in[1];
    const float* W1 = (const float*)d_in[2];  const float* b1 = (const float*)d_in[3];
    const float* W2 = (const float*)d_in[4];  const float* b2 = (const float*)d_in[5];
    const float* Wp = (const float*)d_in[6];  const float* bp = (const float*)d_in[7];
    const float* Wd1 = (const float*)d_in[8]; const float* bd1 = (const float*)d_in[9];
    const float* Wd2 = (const float*)d_in[10]; const float* bd2 = (const float*)d_in[11];
    const float* Wd3 = (const float*)d_in[12]; const float* bd3 = (const float*)d_in[13];

    const int n = in_sizes[0] / 128;   // 50000
    const int E = in_sizes[1] / 2;     // 800000
    const int* row = ei;        // source
    const int* col = ei + E;    // target

    float* out = (float*)d_out;

    const int CH   = 8192;
    const int nwg  = (E + CH - 1) / CH;     // 98
    const int nbuk = (n + 63) >> 6;         // 782

    // workspace layout (aligned)
    char* ws = (char*)d_ws;
    auto alloc = [&](size_t bytes) {
        ws = (char*)(((uintptr_t)ws + 255) & ~(uintptr_t)255);
        char* p = ws; ws += bytes; return (void*)p;
    };
    float* dinv   = (float*)alloc((size_t)n * 4);
    int*   rowptr = (int*)alloc((size_t)(n + 4) * 4);
    int*   boff   = (int*)alloc((size_t)(nbuk + 4) * 4);
    int*   bsum   = (int*)alloc((size_t)nbuk * 4);
    int*   M      = (int*)alloc((size_t)nbuk * nwg * 4);
    int*   csrc   = (int*)alloc((size_t)E * 4);
    float* hs1    = (float*)alloc((size_t)n * 64 * 4);   // overlays ebuf (build)
    float* x1     = (float*)alloc((size_t)n * 64 * 4);
    float* hs2    = (float*)alloc((size_t)n * 32 * 4);
    u16*   wswHi  = (u16*)alloc((size_t)73 * 512 * 2);
    u16*   wswLo  = (u16*)alloc((size_t)73 * 512 * 2);
    int2*  ebuf   = (int2*)hs1;           // dead before gemm1 writes hs1

    const int BS = 256;
    auto blocks = [](long long work, int bs) { return (unsigned)((work + bs - 1) / bs); };
    const int ntiles = (n + 63) / 64;                // 782

    // ---- graph structure: bucketed counting sort (zero global atomics) ----
    bucket_hist<<<nwg, 256, 0, stream>>>(col, M, E, nbuk, nwg);
    col_scan<<<blocks(nbuk, 256), 256, 0, stream>>>(M, bsum, nbuk, nwg);
    bucket_scan<<<1, 1024, 0, stream>>>(bsum, boff, rowptr, nbuk, n, E);
    bucket_scatter<<<nwg, 256, 0, stream>>>(row, col, M, boff, ebuf, E, nwg);
    bucket_finalize<<<nbuk, 256, 0, stream>>>(ebuf, boff, rowptr, csrc, dinv, n);

    // ---- weight swizzle (independent) ----
    wswz_kernel<<<73, 64, 0, stream>>>(Wd1, Wd2, Wd3, Wp, wswHi, wswLo);

    // ---- GCN layer 1: raw_x[128] -> 64 ----
    gemm_gcn<128, 64><<<blocks(n, 64), 256, 0, stream>>>(raw_x, W1, dinv, hs1, n);
    agg_finalize<64, true><<<blocks((long long)n * 16, BS), BS, 0, stream>>>(
        rowptr, csrc, hs1, dinv, b1, x1, n, 64, 0);

    // ---- GCN layer 2: x1[64] -> 32 ----
    gemm_gcn<64, 32><<<blocks(n, 64), 256, 0, stream>>>(x1, W2, dinv, hs2, n);
    agg_finalize<32, false><<<blocks((long long)n * 8, BS), BS, 0, stream>>>(
        rowptr, csrc, hs2, dinv, b2, out, n, 170, 0);   // emb -> out[:,0:32)

    // ---- fully-fused decoder (weights resident in LDS, 2-tile interleave) ----
    dec_fused<<<256, 256, 0, stream>>>(out, wswHi, wswLo, bp, bd1, bd2, bd3, out, n, ntiles);
}

// Round 14
// 232.684 us; speedup vs baseline: 1.4701x; 1.0512x over previous
//
#include <hip/hip_runtime.h>
#include <math.h>

typedef unsigned short u16;
typedef unsigned int u32;
typedef __attribute__((ext_vector_type(8))) short bf8;   // 8 bf16 = 4 VGPR
typedef __attribute__((ext_vector_type(4))) float f4;    // 4 f32 acc

__device__ __forceinline__ u16 bfhi(float x) {
    u32 u = __float_as_uint(x);
    u32 r = u + 0x7FFFu + ((u >> 16) & 1u);   // RNE
    return (u16)(r >> 16);
}
__device__ __forceinline__ float bf2f(u16 h) { return __uint_as_float(((u32)h) << 16); }

// ================= graph build: zero-global-atomic bucketed CSR =================
// bucket = col >> 6 (64 nodes per bucket). CH = 8192 edges per workgroup.

__global__ __launch_bounds__(256) void bucket_hist(const int* __restrict__ col,
                                                   int* __restrict__ M, int E, int nbuk, int nwg) {
    __shared__ int h[1024];
    const int tid = threadIdx.x;
    for (int i = tid; i < 1024; i += 256) h[i] = 0;
    __syncthreads();
    int base = blockIdx.x * 8192;
    for (int i = tid; i < 8192; i += 256) {
        int e = base + i;
        if (e < E) atomicAdd(&h[col[e] >> 6], 1);   // LDS atomic
    }
    __syncthreads();
    for (int b = tid; b < nbuk; b += 256) M[b * nwg + blockIdx.x] = h[b];
}

// per-bucket exclusive scan over workgroups (in place), bucket totals -> bsum
__global__ void col_scan(int* __restrict__ M, int* __restrict__ bsum, int nbuk, int nwg) {
    int b = blockIdx.x * blockDim.x + threadIdx.x;
    if (b >= nbuk) return;
    int s = 0;
    for (int w = 0; w < nwg; ++w) { int t = M[b * nwg + w]; M[b * nwg + w] = s; s += t; }
    bsum[b] = s;
}

// single block: exclusive scan of bucket sums -> boff; boff[nbuk]=E; rowptr[n]=E
__global__ void bucket_scan(const int* __restrict__ bsum, int* __restrict__ boff,
                            int* __restrict__ rowptr, int nbuk, int n, int E) {
    __shared__ int sh[1024];
    const int tid = threadIdx.x;
    int v = (tid < nbuk) ? bsum[tid] : 0;
    sh[tid] = v; __syncthreads();
    for (int off = 1; off < 1024; off <<= 1) {
        int x = sh[tid];
        int w = (tid >= off) ? sh[tid - off] : 0;
        __syncthreads();
        sh[tid] = x + w;
        __syncthreads();
    }
    if (tid < nbuk) boff[tid] = sh[tid] - v;
    if (tid == 0) { boff[nbuk] = E; rowptr[n] = E; }
}

// scatter edges into bucket-sorted ebuf (LDS ranks, no global atomics)
__global__ __launch_bounds__(256) void bucket_scatter(const int* __restrict__ row,
                                                      const int* __restrict__ col,
                                                      const int* __restrict__ M,
                                                      const int* __restrict__ boff,
                                                      int2* __restrict__ ebuf, int E, int nwg) {
    __shared__ int h[1024];
    const int tid = threadIdx.x;
    for (int i = tid; i < 1024; i += 256) h[i] = 0;
    __syncthreads();
    int base = blockIdx.x * 8192;
    for (int i = tid; i < 8192; i += 256) {
        int e = base + i;
        if (e < E) {
            int c = col[e], b = c >> 6;
            int rank = atomicAdd(&h[b], 1);  // LDS
            int slot = boff[b] + M[b * nwg + blockIdx.x] + rank;
            ebuf[slot] = make_int2(c, row[e]);
        }
    }
}

// per-bucket: node histogram -> dinv + rowptr + node-sorted csrc (all bucket-local)
__global__ __launch_bounds__(256) void bucket_finalize(const int2* __restrict__ ebuf,
                                                       const int* __restrict__ boff,
                                                       int* __restrict__ rowptr,
                                                       int* __restrict__ csrc,
                                                       float* __restrict__ dinv, int n) {
    __shared__ int h[64];
    __shared__ int curs[64];
    const int b = blockIdx.x, tid = threadIdx.x;
    const int n0 = b << 6;
    const int beg = boff[b], end = boff[b + 1];
    if (tid < 64) h[tid] = 0;
    __syncthreads();
    for (int i = beg + tid; i < end; i += 256) atomicAdd(&h[ebuf[i].x & 63], 1);
    __syncthreads();
    if (tid < 64) {                    // first wave: 64-lane shfl scan
        int cnt = h[tid];
        int v = cnt;
        for (int off = 1; off < 64; off <<= 1) {
            int w = __shfl_up(v, off);
            if (tid >= off) v += w;
        }
        int cursor = beg + v - cnt;    // exclusive
        curs[tid] = cursor;
        int node = n0 + tid;
        if (node < n) {
            rowptr[node] = cursor;
            dinv[node] = rsqrtf((float)(cnt + 1));   // +1 self loop
        }
    }
    __syncthreads();
    for (int i = beg + tid; i < end; i += 256) {
        int2 e = ebuf[i];
        int slot = atomicAdd(&curs[e.x & 63], 1);    // LDS
        csrc[slot] = e.y;
    }
}

// ---------------- CSR gather aggregation + finalize ----------------
template<int F, bool OV>
__global__ void agg_finalize(const int* __restrict__ rowptr, const int* __restrict__ csrc,
                             const float* __restrict__ hs, const float* __restrict__ dinv,
                             const float* __restrict__ b, float* __restrict__ out,
                             int n, int ostride, int col0) {
    constexpr int L = F / 4;                 // lanes per node
    int tid = blockIdx.x * blockDim.x + threadIdx.x;
    int node = tid / L, lane = tid % L;
    if (node >= n) return;
    int f0 = lane * 4;
    int beg = rowptr[node], end = rowptr[node + 1];
    float4 sum = make_float4(0.f, 0.f, 0.f, 0.f);
    for (int j = beg; j < end; ++j) {
        int s = csrc[j];                     // uniform across the L-lane group
        float4 v = *(const float4*)&hs[(size_t)s * F + f0];
        sum.x += v.x; sum.y += v.y; sum.z += v.z; sum.w += v.w;
    }
    float4 self = *(const float4*)&hs[(size_t)node * F + f0];
    float di = dinv[node];
    float r0 = fmaxf(di * (sum.x + self.x) + b[f0 + 0], 0.f);
    float r1 = fmaxf(di * (sum.y + self.y) + b[f0 + 1], 0.f);
    float r2 = fmaxf(di * (sum.z + self.z) + b[f0 + 2], 0.f);
    float r3 = fmaxf(di * (sum.w + self.w) + b[f0 + 3], 0.f);
    float* op = &out[(size_t)node * ostride + col0 + f0];
    if (OV) {
        *(float4*)op = make_float4(r0, r1, r2, r3);
    } else {
        op[0] = r0; op[1] = r1; op[2] = r2; op[3] = r3;
    }
}

// ---------------- GCN dense: out[r,c] = dinv[r] * sum_k x[r,k]*W[k,c] ----------------
template<int K, int OC>
__global__ __launch_bounds__(256) void gemm_gcn(
    const float* __restrict__ x, const float* __restrict__ W,
    const float* __restrict__ dinv, float* __restrict__ outp, int n) {
    constexpr int CG = OC / 8;        // col groups
    constexpr int RG = 256 / CG;      // row groups
    constexpr int ROWS = 64 / RG;     // rows per thread
    __shared__ float xL[64][K + 4];

    const int tid = threadIdx.x;
    const int cg = tid % CG, rg = tid / CG;
    const int c0 = cg * 8, r0 = rg * ROWS;
    const int row0 = blockIdx.x * 64;

#pragma unroll
    for (int i = 0; i < K / 16; ++i) {
        int e = tid + i * 256;
        int r = e / (K / 4), q = e % (K / 4);
        float4 v = make_float4(0.f, 0.f, 0.f, 0.f);
        if (row0 + r < n) v = *(const float4*)&x[(size_t)(row0 + r) * K + q * 4];
        *(float4*)&xL[r][q * 4] = v;
    }
    __syncthreads();

    float acc[ROWS][8];
#pragma unroll
    for (int r = 0; r < ROWS; ++r)
#pragma unroll
        for (int c = 0; c < 8; ++c) acc[r][c] = 0.f;

#pragma unroll 8
    for (int k = 0; k < K; ++k) {
        float4 w0 = *(const float4*)&W[(size_t)k * OC + c0];
        float4 w1 = *(const float4*)&W[(size_t)k * OC + c0 + 4];
        float wv[8] = {w0.x, w0.y, w0.z, w0.w, w1.x, w1.y, w1.z, w1.w};
        float xv[ROWS];
#pragma unroll
        for (int r = 0; r < ROWS; ++r) xv[r] = xL[r0 + r][k];
#pragma unroll
        for (int r = 0; r < ROWS; ++r)
#pragma unroll
            for (int c = 0; c < 8; ++c) acc[r][c] = fmaf(xv[r], wv[c], acc[r][c]);
    }

#pragma unroll
    for (int r = 0; r < ROWS; ++r) {
        int gr = row0 + r0 + r;
        if (gr >= n) continue;
        float di = dinv[gr];
        float* op = &outp[(size_t)gr * OC + c0];
        *(float4*)op = make_float4(acc[r][0] * di, acc[r][1] * di, acc[r][2] * di, acc[r][3] * di);
        *(float4*)(op + 4) = make_float4(acc[r][4] * di, acc[r][5] * di, acc[r][6] * di, acc[r][7] * di);
    }
}

// ---------------- weight pre-swizzle into MFMA B-fragment order ----------------
// B-frag for mfma_f32_16x16x32_bf16: lane l holds B[kt*32 + (l>>4)*8 + j][ct*16 + (l&15)], j=0..7
// tiles: 0..7 Wd1(32x128), 8..39 Wd2(128x128), 40..71 Wd3(128x128), 72 Wp(32x10 pad16)
__global__ void wswz_kernel(const float* __restrict__ Wd1, const float* __restrict__ Wd2,
                            const float* __restrict__ Wd3, const float* __restrict__ Wp,
                            u16* __restrict__ whi, u16* __restrict__ wlo) {
    int t = blockIdx.x, l = threadIdx.x;   // 73 blocks x 64 threads
    const float* W; int C, kt, ct;
    if (t < 8)       { W = Wd1; C = 128; kt = 0;           ct = t; }
    else if (t < 40) { W = Wd2; C = 128; kt = (t - 8) >> 3; ct = (t - 8) & 7; }
    else if (t < 72) { W = Wd3; C = 128; kt = (t - 40) >> 3; ct = (t - 40) & 7; }
    else             { W = Wp;  C = 10;  kt = 0;           ct = 0; }
    int kbase = kt * 32 + (l >> 4) * 8;
    int c = ct * 16 + (l & 15);
    size_t base = (size_t)t * 512 + (size_t)l * 8;
#pragma unroll
    for (int j = 0; j < 8; ++j) {
        float v = (c < C) ? W[(size_t)(kbase + j) * C + c] : 0.f;
        u16 h = bfhi(v);
        whi[base + j] = (u16)h;
        wlo[base + j] = bfhi(v - bf2f(h));
    }
}

// ---------------- fully-fused MFMA decoder: 8 waves, 128-row tiles ----------------
// ALL 73 weight tiles resident in LDS (149.5 KB). 512 thr = 8 waves = 2 waves/SIMD
// so cross-wave overlap hides scr-handoff and MFMA latency (1-wave/SIMD was the
// R12 limiter). h1/h2 handoff via 16-col scr slices ([128][20] u32 = 10.2 KB):
// write slice0 -> lanes lg<2 read -> write slice1 -> lanes lg>=2 read (per-wave
// in-order DS + may-alias ordering; wave-private rows -> no barriers).
// LDS total 159.7 KB -> 1 block/CU.
__global__ __launch_bounds__(512, 1) void dec_fused(
    const float* __restrict__ obuf,
    const u16* __restrict__ whi, const u16* __restrict__ wlo,
    const float* __restrict__ bp, const float* __restrict__ bd1,
    const float* __restrict__ bd2, const float* __restrict__ bd3,
    float* __restrict__ out, int n, int ntiles) {
    __shared__ __align__(16) u16 wbH[73][512];   // 74752 B
    __shared__ __align__(16) u16 wbL[73][512];   // 74752 B
    __shared__ __align__(16) u32 scr[128][20];   // 10240 B

    const int tid = threadIdx.x;
    const int l = tid & 63, wv = tid >> 6;       // 8 waves
    const int lr = l & 15, lg = l >> 4;
    const int wrow = wv * 16;                    // wave strip within 128-row tile

    // stage all weights once per block
    for (int i = tid; i < 73 * 64; i += 512) {
        ((int4*)wbH)[i] = ((const int4*)whi)[i];
        ((int4*)wbL)[i] = ((const int4*)wlo)[i];
    }
    __syncthreads();

    for (int t = blockIdx.x; t < ntiles; t += gridDim.x) {
        const int row0 = t * 128;
        int arow = row0 + wrow + lr; if (arow >= n) arow = n - 1;   // clamp; stores guarded

        // ---- A-frag from emb (out[:,0:32)) ----
        const float* src = &obuf[(size_t)arow * 170 + lg * 8];
        bf8 aH, aL;
#pragma unroll
        for (int i = 0; i < 8; i += 2) {
            float2 v = *(const float2*)(src + i);
            u16 h0 = bfhi(v.x), h1 = bfhi(v.y);
            ((u16*)&aH)[i] = h0;     ((u16*)&aH)[i + 1] = h1;
            ((u16*)&aL)[i] = bfhi(v.x - bf2f(h0));
            ((u16*)&aL)[i + 1] = bfhi(v.y - bf2f(h1));
        }

        // ---- stage 1: h1 = emb @ Wd1 (tiles 0..7), head = emb @ Wp (tile 72) ----
        f4 acc1[8];
#pragma unroll
        for (int ct = 0; ct < 8; ++ct) {
            bf8 bH = *(const bf8*)&wbH[ct][l * 8];
            bf8 bL = *(const bf8*)&wbL[ct][l * 8];
            f4 a = (f4){0.f, 0.f, 0.f, 0.f};
            a = __builtin_amdgcn_mfma_f32_16x16x32_bf16(aH, bH, a, 0, 0, 0);
            a = __builtin_amdgcn_mfma_f32_16x16x32_bf16(aL, bH, a, 0, 0, 0);
            a = __builtin_amdgcn_mfma_f32_16x16x32_bf16(aH, bL, a, 0, 0, 0);
            acc1[ct] = a;
        }
        {   // head
            bf8 pH = *(const bf8*)&wbH[72][l * 8];
            bf8 pL = *(const bf8*)&wbL[72][l * 8];
            f4 p = (f4){0.f, 0.f, 0.f, 0.f};
            p = __builtin_amdgcn_mfma_f32_16x16x32_bf16(aH, pH, p, 0, 0, 0);
            p = __builtin_amdgcn_mfma_f32_16x16x32_bf16(aL, pH, p, 0, 0, 0);
            p = __builtin_amdgcn_mfma_f32_16x16x32_bf16(aH, pL, p, 0, 0, 0);
            if (lr < 10) {
                float bpv = bp[lr];
#pragma unroll
                for (int rg = 0; rg < 4; ++rg) {
                    int g = row0 + wrow + lg * 4 + rg;
                    if (g < n) out[(size_t)g * 170 + 32 + lr] = p[rg] + bpv;
                }
            }
        }

        // ---- stage 2: h2 = relu(h1+bd1) @ Wd2 (tiles 8..39), 2-step scr handoff ----
        f4 acc2[8];
#pragma unroll
        for (int ct = 0; ct < 8; ++ct) acc2[ct] = (f4){0.f, 0.f, 0.f, 0.f};
#pragma unroll
        for (int kt = 0; kt < 4; ++kt) {
            u32 w[8];
            {   // slice 0: ct = kt*2 (k-cols [kt*32, kt*32+16))
                int ct = kt * 2;
                float bv = bd1[ct * 16 + lr];
#pragma unroll
                for (int rg = 0; rg < 4; ++rg) {
                    float v = fmaxf(acc1[ct][rg] + bv, 0.f);
                    u16 vh = bfhi(v), vl = bfhi(v - bf2f(vh));
                    scr[wrow + lg * 4 + rg][lr] = (u32)vh | ((u32)vl << 16);
                }
            }
            if (lg < 2) {   // lanes whose k-range lies in slice 0
                *(uint4*)&w[0] = *(const uint4*)&scr[wrow + lr][lg * 8];
                *(uint4*)&w[4] = *(const uint4*)&scr[wrow + lr][lg * 8 + 4];
            }
            {   // slice 1: ct = kt*2+1 (k-cols [kt*32+16, kt*32+32))
                int ct = kt * 2 + 1;
                float bv = bd1[ct * 16 + lr];
#pragma unroll
                for (int rg = 0; rg < 4; ++rg) {
                    float v = fmaxf(acc1[ct][rg] + bv, 0.f);
                    u16 vh = bfhi(v), vl = bfhi(v - bf2f(vh));
                    scr[wrow + lg * 4 + rg][lr] = (u32)vh | ((u32)vl << 16);
                }
            }
            if (lg >= 2) {
                *(uint4*)&w[0] = *(const uint4*)&scr[wrow + lr][(lg - 2) * 8];
                *(uint4*)&w[4] = *(const uint4*)&scr[wrow + lr][(lg - 2) * 8 + 4];
            }
            bf8 a2H, a2L;
#pragma unroll
            for (int j = 0; j < 8; ++j) {
                ((u16*)&a2H)[j] = (u16)(w[j] & 0xffffu);
                ((u16*)&a2L)[j] = (u16)(w[j] >> 16);
            }
#pragma unroll
            for (int ct = 0; ct < 8; ++ct) {
                bf8 bH = *(const bf8*)&wbH[8 + kt * 8 + ct][l * 8];
                bf8 bL = *(const bf8*)&wbL[8 + kt * 8 + ct][l * 8];
                acc2[ct] = __builtin_amdgcn_mfma_f32_16x16x32_bf16(a2H, bH, acc2[ct], 0, 0, 0);
                acc2[ct] = __builtin_amdgcn_mfma_f32_16x16x32_bf16(a2L, bH, acc2[ct], 0, 0, 0);
                acc2[ct] = __builtin_amdgcn_mfma_f32_16x16x32_bf16(a2H, bL, acc2[ct], 0, 0, 0);
            }
        }

        // ---- stage 3: dec = relu(h2+bd2) @ Wd3 (tiles 40..71) ----
        f4 acc3[8];
#pragma unroll
        for (int ct = 0; ct < 8; ++ct) acc3[ct] = (f4){0.f, 0.f, 0.f, 0.f};
#pragma unroll
        for (int kt = 0; kt < 4; ++kt) {
            u32 w[8];
            {
                int ct = kt * 2;
                float bv = bd2[ct * 16 + lr];
#pragma unroll
                for (int rg = 0; rg < 4; ++rg) {
                    float v = fmaxf(acc2[ct][rg] + bv, 0.f);
                    u16 vh = bfhi(v), vl = bfhi(v - bf2f(vh));
                    scr[wrow + lg * 4 + rg][lr] = (u32)vh | ((u32)vl << 16);
                }
            }
            if (lg < 2) {
                *(uint4*)&w[0] = *(const uint4*)&scr[wrow + lr][lg * 8];
                *(uint4*)&w[4] = *(const uint4*)&scr[wrow + lr][lg * 8 + 4];
            }
            {
                int ct = kt * 2 + 1;
                float bv = bd2[ct * 16 + lr];
#pragma unroll
                for (int rg = 0; rg < 4; ++rg) {
                    float v = fmaxf(acc2[ct][rg] + bv, 0.f);
                    u16 vh = bfhi(v), vl = bfhi(v - bf2f(vh));
                    scr[wrow + lg * 4 + rg][lr] = (u32)vh | ((u32)vl << 16);
                }
            }
            if (lg >= 2) {
                *(uint4*)&w[0] = *(const uint4*)&scr[wrow + lr][(lg - 2) * 8];
                *(uint4*)&w[4] = *(const uint4*)&scr[wrow + lr][(lg - 2) * 8 + 4];
            }
            bf8 a3H, a3L;
#pragma unroll
            for (int j = 0; j < 8; ++j) {
                ((u16*)&a3H)[j] = (u16)(w[j] & 0xffffu);
                ((u16*)&a3L)[j] = (u16)(w[j] >> 16);
            }
#pragma unroll
            for (int ct = 0; ct < 8; ++ct) {
                bf8 bH = *(const bf8*)&wbH[40 + kt * 8 + ct][l * 8];
                bf8 bL = *(const bf8*)&wbL[40 + kt * 8 + ct][l * 8];
                acc3[ct] = __builtin_amdgcn_mfma_f32_16x16x32_bf16(a3H, bH, acc3[ct], 0, 0, 0);
                acc3[ct] = __builtin_amdgcn_mfma_f32_16x16x32_bf16(a3L, bH, acc3[ct], 0, 0, 0);
                acc3[ct] = __builtin_amdgcn_mfma_f32_16x16x32_bf16(a3H, bL, acc3[ct], 0, 0, 0);
            }
        }

        // ---- epilogue: softplus -> out[:,42:170) ----
#pragma unroll
        for (int ct = 0; ct < 8; ++ct) {
            float bv = bd3[ct * 16 + lr];
#pragma unroll
            for (int rg = 0; rg < 4; ++rg) {
                int g = row0 + wrow + lg * 4 + rg;
                if (g < n) {
                    float v = acc3[ct][rg] + bv;
                    v = fmaxf(v, 0.f) + __logf(1.f + __expf(-fabsf(v)));
                    out[(size_t)g * 170 + 42 + ct * 16 + lr] = v;
                }
            }
        }
    }
}

// ---------------- launch ----------------

extern "C" void kernel_launch(void* const* d_in, const int* in_sizes, int n_in,
                              void* d_out, int out_size, void* d_ws, size_t ws_size,
                              hipStream_t stream) {
    const float* raw_x = (const float*)d_in[0];
    const int*   ei    = (const int*)d_in[1];
    const float* W1 = (const float*)d_in[2];  const float* b1 = (const float*)d_in[3];
    const float* W2 = (const float*)d_in[4];  const float* b2 = (const float*)d_in[5];
    const float* Wp = (const float*)d_in[6];  const float* bp = (const float*)d_in[7];
    const float* Wd1 = (const float*)d_in[8]; const float* bd1 = (const float*)d_in[9];
    const float* Wd2 = (const float*)d_in[10]; const float* bd2 = (const float*)d_in[11];
    const float* Wd3 = (const float*)d_in[12]; const float* bd3 = (const float*)d_in[13];

    const int n = in_sizes[0] / 128;   // 50000
    const int E = in_sizes[1] / 2;     // 800000
    const int* row = ei;        // source
    const int* col = ei + E;    // target

    float* out = (float*)d_out;

    const int CH   = 8192;
    const int nwg  = (E + CH - 1) / CH;     // 98
    const int nbuk = (n + 63) >> 6;         // 782

    // workspace layout (aligned)
    char* ws = (char*)d_ws;
    auto alloc = [&](size_t bytes) {
        ws = (char*)(((uintptr_t)ws + 255) & ~(uintptr_t)255);
        char* p = ws; ws += bytes; return (void*)p;
    };
    float* dinv   = (float*)alloc((size_t)n * 4);
    int*   rowptr = (int*)alloc((size_t)(n + 4) * 4);
    int*   boff   = (int*)alloc((size_t)(nbuk + 4) * 4);
    int*   bsum   = (int*)alloc((size_t)nbuk * 4);
    int*   M      = (int*)alloc((size_t)nbuk * nwg * 4);
    int*   csrc   = (int*)alloc((size_t)E * 4);
    float* hs1    = (float*)alloc((size_t)n * 64 * 4);   // overlays ebuf (build)
    float* x1     = (float*)alloc((size_t)n * 64 * 4);
    float* hs2    = (float*)alloc((size_t)n * 32 * 4);
    u16*   wswHi  = (u16*)alloc((size_t)73 * 512 * 2);
    u16*   wswLo  = (u16*)alloc((size_t)73 * 512 * 2);
    int2*  ebuf   = (int2*)hs1;           // dead before gemm1 writes hs1

    const int BS = 256;
    auto blocks = [](long long work, int bs) { return (unsigned)((work + bs - 1) / bs); };
    const int ntiles = (n + 127) / 128;              // 391 (128-row decoder tiles)

    // ---- graph structure: bucketed counting sort (zero global atomics) ----
    bucket_hist<<<nwg, 256, 0, stream>>>(col, M, E, nbuk, nwg);
    col_scan<<<blocks(nbuk, 256), 256, 0, stream>>>(M, bsum, nbuk, nwg);
    bucket_scan<<<1, 1024, 0, stream>>>(bsum, boff, rowptr, nbuk, n, E);
    bucket_scatter<<<nwg, 256, 0, stream>>>(row, col, M, boff, ebuf, E, nwg);
    bucket_finalize<<<nbuk, 256, 0, stream>>>(ebuf, boff, rowptr, csrc, dinv, n);

    // ---- weight swizzle (independent) ----
    wswz_kernel<<<73, 64, 0, stream>>>(Wd1, Wd2, Wd3, Wp, wswHi, wswLo);

    // ---- GCN layer 1: raw_x[128] -> 64 ----
    gemm_gcn<128, 64><<<blocks(n, 64), 256, 0, stream>>>(raw_x, W1, dinv, hs1, n);
    agg_finalize<64, true><<<blocks((long long)n * 16, BS), BS, 0, stream>>>(
        rowptr, csrc, hs1, dinv, b1, x1, n, 64, 0);

    // ---- GCN layer 2: x1[64] -> 32 ----
    gemm_gcn<64, 32><<<blocks(n, 64), 256, 0, stream>>>(x1, W2, dinv, hs2, n);
    agg_finalize<32, false><<<blocks((long long)n * 8, BS), BS, 0, stream>>>(
        rowptr, csrc, hs2, dinv, b2, out, n, 170, 0);   // emb -> out[:,0:32)

    // ---- fully-fused decoder: 8 waves/block, weights resident in LDS ----
    dec_fused<<<256, 512, 0, stream>>>(out, wswHi, wswLo, bp, bd1, bd2, bd3, out, n, ntiles);
}

// Round 15
// 219.159 us; speedup vs baseline: 1.5608x; 1.0617x over previous
//
#include <hip/hip_runtime.h>
#include <math.h>

typedef unsigned short u16;
typedef unsigned int u32;
typedef __attribute__((ext_vector_type(8))) short bf8;   // 8 bf16 = 4 VGPR
typedef __attribute__((ext_vector_type(4))) float f4;    // 4 f32 acc

__device__ __forceinline__ u16 bfhi(float x) {
    u32 u = __float_as_uint(x);
    u32 r = u + 0x7FFFu + ((u >> 16) & 1u);   // RNE
    return (u16)(r >> 16);
}
__device__ __forceinline__ float bf2f(u16 h) { return __uint_as_float(((u32)h) << 16); }

// ================= graph build: zero-global-atomic bucketed CSR =================
// bucket = col >> 6 (64 nodes per bucket). CH = 8192 edges per workgroup.

__global__ __launch_bounds__(256) void bucket_hist(const int* __restrict__ col,
                                                   int* __restrict__ M, int E, int nbuk, int nwg) {
    __shared__ int h[1024];
    const int tid = threadIdx.x;
    for (int i = tid; i < 1024; i += 256) h[i] = 0;
    __syncthreads();
    int base = blockIdx.x * 8192;
    for (int i = tid; i < 8192; i += 256) {
        int e = base + i;
        if (e < E) atomicAdd(&h[col[e] >> 6], 1);   // LDS atomic
    }
    __syncthreads();
    for (int b = tid; b < nbuk; b += 256) M[b * nwg + blockIdx.x] = h[b];
}

// per-bucket exclusive scan over workgroups (in place), bucket totals -> bsum
__global__ void col_scan(int* __restrict__ M, int* __restrict__ bsum, int nbuk, int nwg) {
    int b = blockIdx.x * blockDim.x + threadIdx.x;
    if (b >= nbuk) return;
    int s = 0;
    for (int w = 0; w < nwg; ++w) { int t = M[b * nwg + w]; M[b * nwg + w] = s; s += t; }
    bsum[b] = s;
}

// single block: exclusive scan of bucket sums -> boff; boff[nbuk]=E; rowptr[n]=E
__global__ void bucket_scan(const int* __restrict__ bsum, int* __restrict__ boff,
                            int* __restrict__ rowptr, int nbuk, int n, int E) {
    __shared__ int sh[1024];
    const int tid = threadIdx.x;
    int v = (tid < nbuk) ? bsum[tid] : 0;
    sh[tid] = v; __syncthreads();
    for (int off = 1; off < 1024; off <<= 1) {
        int x = sh[tid];
        int w = (tid >= off) ? sh[tid - off] : 0;
        __syncthreads();
        sh[tid] = x + w;
        __syncthreads();
    }
    if (tid < nbuk) boff[tid] = sh[tid] - v;
    if (tid == 0) { boff[nbuk] = E; rowptr[n] = E; }
}

// scatter edges into bucket-sorted ebuf (LDS ranks, no global atomics)
__global__ __launch_bounds__(256) void bucket_scatter(const int* __restrict__ row,
                                                      const int* __restrict__ col,
                                                      const int* __restrict__ M,
                                                      const int* __restrict__ boff,
                                                      int2* __restrict__ ebuf, int E, int nwg) {
    __shared__ int h[1024];
    const int tid = threadIdx.x;
    for (int i = tid; i < 1024; i += 256) h[i] = 0;
    __syncthreads();
    int base = blockIdx.x * 8192;
    for (int i = tid; i < 8192; i += 256) {
        int e = base + i;
        if (e < E) {
            int c = col[e], b = c >> 6;
            int rank = atomicAdd(&h[b], 1);  // LDS
            int slot = boff[b] + M[b * nwg + blockIdx.x] + rank;
            ebuf[slot] = make_int2(c, row[e]);
        }
    }
}

// per-bucket: node histogram -> dinv + rowptr + node-sorted csrc (all bucket-local)
__global__ __launch_bounds__(256) void bucket_finalize(const int2* __restrict__ ebuf,
                                                       const int* __restrict__ boff,
                                                       int* __restrict__ rowptr,
                                                       int* __restrict__ csrc,
                                                       float* __restrict__ dinv, int n) {
    __shared__ int h[64];
    __shared__ int curs[64];
    const int b = blockIdx.x, tid = threadIdx.x;
    const int n0 = b << 6;
    const int beg = boff[b], end = boff[b + 1];
    if (tid < 64) h[tid] = 0;
    __syncthreads();
    for (int i = beg + tid; i < end; i += 256) atomicAdd(&h[ebuf[i].x & 63], 1);
    __syncthreads();
    if (tid < 64) {                    // first wave: 64-lane shfl scan
        int cnt = h[tid];
        int v = cnt;
        for (int off = 1; off < 64; off <<= 1) {
            int w = __shfl_up(v, off);
            if (tid >= off) v += w;
        }
        int cursor = beg + v - cnt;    // exclusive
        curs[tid] = cursor;
        int node = n0 + tid;
        if (node < n) {
            rowptr[node] = cursor;
            dinv[node] = rsqrtf((float)(cnt + 1));   // +1 self loop
        }
    }
    __syncthreads();
    for (int i = beg + tid; i < end; i += 256) {
        int2 e = ebuf[i];
        int slot = atomicAdd(&curs[e.x & 63], 1);    // LDS
        csrc[slot] = e.y;
    }
}

// ---------------- CSR gather aggregation + finalize (4-way ILP unroll) ----------------
template<int F, bool OV>
__global__ void agg_finalize(const int* __restrict__ rowptr, const int* __restrict__ csrc,
                             const float* __restrict__ hs, const float* __restrict__ dinv,
                             const float* __restrict__ b, float* __restrict__ out,
                             int n, int ostride, int col0) {
    constexpr int L = F / 4;                 // lanes per node
    int tid = blockIdx.x * blockDim.x + threadIdx.x;
    int node = tid / L, lane = tid % L;
    if (node >= n) return;
    int f0 = lane * 4;
    int beg = rowptr[node], end = rowptr[node + 1];
    float4 sum = make_float4(0.f, 0.f, 0.f, 0.f);
    int j = beg;
    // 4-way unroll: 4 independent gathers in flight per group
    for (; j + 3 < end; j += 4) {
        int s0 = csrc[j], s1 = csrc[j + 1], s2 = csrc[j + 2], s3 = csrc[j + 3];
        float4 v0 = *(const float4*)&hs[(size_t)s0 * F + f0];
        float4 v1 = *(const float4*)&hs[(size_t)s1 * F + f0];
        float4 v2 = *(const float4*)&hs[(size_t)s2 * F + f0];
        float4 v3 = *(const float4*)&hs[(size_t)s3 * F + f0];
        sum.x += (v0.x + v1.x) + (v2.x + v3.x);
        sum.y += (v0.y + v1.y) + (v2.y + v3.y);
        sum.z += (v0.z + v1.z) + (v2.z + v3.z);
        sum.w += (v0.w + v1.w) + (v2.w + v3.w);
    }
    for (; j < end; ++j) {
        int s = csrc[j];
        float4 v = *(const float4*)&hs[(size_t)s * F + f0];
        sum.x += v.x; sum.y += v.y; sum.z += v.z; sum.w += v.w;
    }
    float4 self = *(const float4*)&hs[(size_t)node * F + f0];
    float di = dinv[node];
    float r0 = fmaxf(di * (sum.x + self.x) + b[f0 + 0], 0.f);
    float r1 = fmaxf(di * (sum.y + self.y) + b[f0 + 1], 0.f);
    float r2 = fmaxf(di * (sum.z + self.z) + b[f0 + 2], 0.f);
    float r3 = fmaxf(di * (sum.w + self.w) + b[f0 + 3], 0.f);
    float* op = &out[(size_t)node * ostride + col0 + f0];
    if (OV) {
        *(float4*)op = make_float4(r0, r1, r2, r3);
    } else {
        op[0] = r0; op[1] = r1; op[2] = r2; op[3] = r3;
    }
}

// ---------------- GCN dense: out[r,c] = dinv[r] * sum_k x[r,k]*W[k,c] ----------------
template<int K, int OC>
__global__ __launch_bounds__(256) void gemm_gcn(
    const float* __restrict__ x, const float* __restrict__ W,
    const float* __restrict__ dinv, float* __restrict__ outp, int n) {
    constexpr int CG = OC / 8;        // col groups
    constexpr int RG = 256 / CG;      // row groups
    constexpr int ROWS = 64 / RG;     // rows per thread
    __shared__ float xL[64][K + 4];

    const int tid = threadIdx.x;
    const int cg = tid % CG, rg = tid / CG;
    const int c0 = cg * 8, r0 = rg * ROWS;
    const int row0 = blockIdx.x * 64;

#pragma unroll
    for (int i = 0; i < K / 16; ++i) {
        int e = tid + i * 256;
        int r = e / (K / 4), q = e % (K / 4);
        float4 v = make_float4(0.f, 0.f, 0.f, 0.f);
        if (row0 + r < n) v = *(const float4*)&x[(size_t)(row0 + r) * K + q * 4];
        *(float4*)&xL[r][q * 4] = v;
    }
    __syncthreads();

    float acc[ROWS][8];
#pragma unroll
    for (int r = 0; r < ROWS; ++r)
#pragma unroll
        for (int c = 0; c < 8; ++c) acc[r][c] = 0.f;

#pragma unroll 8
    for (int k = 0; k < K; ++k) {
        float4 w0 = *(const float4*)&W[(size_t)k * OC + c0];
        float4 w1 = *(const float4*)&W[(size_t)k * OC + c0 + 4];
        float wv[8] = {w0.x, w0.y, w0.z, w0.w, w1.x, w1.y, w1.z, w1.w};
        float xv[ROWS];
#pragma unroll
        for (int r = 0; r < ROWS; ++r) xv[r] = xL[r0 + r][k];
#pragma unroll
        for (int r = 0; r < ROWS; ++r)
#pragma unroll
            for (int c = 0; c < 8; ++c) acc[r][c] = fmaf(xv[r], wv[c], acc[r][c]);
    }

#pragma unroll
    for (int r = 0; r < ROWS; ++r) {
        int gr = row0 + r0 + r;
        if (gr >= n) continue;
        float di = dinv[gr];
        float* op = &outp[(size_t)gr * OC + c0];
        *(float4*)op = make_float4(acc[r][0] * di, acc[r][1] * di, acc[r][2] * di, acc[r][3] * di);
        *(float4*)(op + 4) = make_float4(acc[r][4] * di, acc[r][5] * di, acc[r][6] * di, acc[r][7] * di);
    }
}

// ---------------- weight pre-swizzle into MFMA B-fragment order ----------------
// B-frag for mfma_f32_16x16x32_bf16: lane l holds B[kt*32 + (l>>4)*8 + j][ct*16 + (l&15)], j=0..7
// tiles: 0..7 Wd1(32x128), 8..39 Wd2(128x128), 40..71 Wd3(128x128), 72 Wp(32x10 pad16)
__global__ void wswz_kernel(const float* __restrict__ Wd1, const float* __restrict__ Wd2,
                            const float* __restrict__ Wd3, const float* __restrict__ Wp,
                            u16* __restrict__ whi, u16* __restrict__ wlo) {
    int t = blockIdx.x, l = threadIdx.x;   // 73 blocks x 64 threads
    const float* W; int C, kt, ct;
    if (t < 8)       { W = Wd1; C = 128; kt = 0;           ct = t; }
    else if (t < 40) { W = Wd2; C = 128; kt = (t - 8) >> 3; ct = (t - 8) & 7; }
    else if (t < 72) { W = Wd3; C = 128; kt = (t - 40) >> 3; ct = (t - 40) & 7; }
    else             { W = Wp;  C = 10;  kt = 0;           ct = 0; }
    int kbase = kt * 32 + (l >> 4) * 8;
    int c = ct * 16 + (l & 15);
    size_t base = (size_t)t * 512 + (size_t)l * 8;
#pragma unroll
    for (int j = 0; j < 8; ++j) {
        float v = (c < C) ? W[(size_t)(kbase + j) * C + c] : 0.f;
        u16 h = bfhi(v);
        whi[base + j] = (u16)h;
        wlo[base + j] = bfhi(v - bf2f(h));
    }
}

// ---------------- fully-fused MFMA decoder: 8 waves, 128-row tiles ----------------
// ALL 73 weight tiles resident in LDS (149.5 KB). 512 thr = 8 waves = 2 waves/SIMD
// so cross-wave overlap hides scr-handoff and MFMA latency. h1/h2 handoff via
// 16-col scr slices ([128][20] u32 = 10.2 KB). LDS total 159.7 KB -> 1 block/CU.
__global__ __launch_bounds__(512, 1) void dec_fused(
    const float* __restrict__ obuf,
    const u16* __restrict__ whi, const u16* __restrict__ wlo,
    const float* __restrict__ bp, const float* __restrict__ bd1,
    const float* __restrict__ bd2, const float* __restrict__ bd3,
    float* __restrict__ out, int n, int ntiles) {
    __shared__ __align__(16) u16 wbH[73][512];   // 74752 B
    __shared__ __align__(16) u16 wbL[73][512];   // 74752 B
    __shared__ __align__(16) u32 scr[128][20];   // 10240 B

    const int tid = threadIdx.x;
    const int l = tid & 63, wv = tid >> 6;       // 8 waves
    const int lr = l & 15, lg = l >> 4;
    const int wrow = wv * 16;                    // wave strip within 128-row tile

    // stage all weights once per block
    for (int i = tid; i < 73 * 64; i += 512) {
        ((int4*)wbH)[i] = ((const int4*)whi)[i];
        ((int4*)wbL)[i] = ((const int4*)wlo)[i];
    }
    __syncthreads();

    for (int t = blockIdx.x; t < ntiles; t += gridDim.x) {
        const int row0 = t * 128;
        int arow = row0 + wrow + lr; if (arow >= n) arow = n - 1;   // clamp; stores guarded

        // ---- A-frag from emb (out[:,0:32)) ----
        const float* src = &obuf[(size_t)arow * 170 + lg * 8];
        bf8 aH, aL;
#pragma unroll
        for (int i = 0; i < 8; i += 2) {
            float2 v = *(const float2*)(src + i);
            u16 h0 = bfhi(v.x), h1 = bfhi(v.y);
            ((u16*)&aH)[i] = h0;     ((u16*)&aH)[i + 1] = h1;
            ((u16*)&aL)[i] = bfhi(v.x - bf2f(h0));
            ((u16*)&aL)[i + 1] = bfhi(v.y - bf2f(h1));
        }

        // ---- stage 1: h1 = emb @ Wd1 (tiles 0..7), head = emb @ Wp (tile 72) ----
        f4 acc1[8];
#pragma unroll
        for (int ct = 0; ct < 8; ++ct) {
            bf8 bH = *(const bf8*)&wbH[ct][l * 8];
            bf8 bL = *(const bf8*)&wbL[ct][l * 8];
            f4 a = (f4){0.f, 0.f, 0.f, 0.f};
            a = __builtin_amdgcn_mfma_f32_16x16x32_bf16(aH, bH, a, 0, 0, 0);
            a = __builtin_amdgcn_mfma_f32_16x16x32_bf16(aL, bH, a, 0, 0, 0);
            a = __builtin_amdgcn_mfma_f32_16x16x32_bf16(aH, bL, a, 0, 0, 0);
            acc1[ct] = a;
        }
        {   // head
            bf8 pH = *(const bf8*)&wbH[72][l * 8];
            bf8 pL = *(const bf8*)&wbL[72][l * 8];
            f4 p = (f4){0.f, 0.f, 0.f, 0.f};
            p = __builtin_amdgcn_mfma_f32_16x16x32_bf16(aH, pH, p, 0, 0, 0);
            p = __builtin_amdgcn_mfma_f32_16x16x32_bf16(aL, pH, p, 0, 0, 0);
            p = __builtin_amdgcn_mfma_f32_16x16x32_bf16(aH, pL, p, 0, 0, 0);
            if (lr < 10) {
                float bpv = bp[lr];
#pragma unroll
                for (int rg = 0; rg < 4; ++rg) {
                    int g = row0 + wrow + lg * 4 + rg;
                    if (g < n) out[(size_t)g * 170 + 32 + lr] = p[rg] + bpv;
                }
            }
        }

        // ---- stage 2: h2 = relu(h1+bd1) @ Wd2 (tiles 8..39), 2-step scr handoff ----
        f4 acc2[8];
#pragma unroll
        for (int ct = 0; ct < 8; ++ct) acc2[ct] = (f4){0.f, 0.f, 0.f, 0.f};
#pragma unroll
        for (int kt = 0; kt < 4; ++kt) {
            u32 w[8];
            {   // slice 0: ct = kt*2 (k-cols [kt*32, kt*32+16))
                int ct = kt * 2;
                float bv = bd1[ct * 16 + lr];
#pragma unroll
                for (int rg = 0; rg < 4; ++rg) {
                    float v = fmaxf(acc1[ct][rg] + bv, 0.f);
                    u16 vh = bfhi(v), vl = bfhi(v - bf2f(vh));
                    scr[wrow + lg * 4 + rg][lr] = (u32)vh | ((u32)vl << 16);
                }
            }
            if (lg < 2) {   // lanes whose k-range lies in slice 0
                *(uint4*)&w[0] = *(const uint4*)&scr[wrow + lr][lg * 8];
                *(uint4*)&w[4] = *(const uint4*)&scr[wrow + lr][lg * 8 + 4];
            }
            {   // slice 1: ct = kt*2+1 (k-cols [kt*32+16, kt*32+32))
                int ct = kt * 2 + 1;
                float bv = bd1[ct * 16 + lr];
#pragma unroll
                for (int rg = 0; rg < 4; ++rg) {
                    float v = fmaxf(acc1[ct][rg] + bv, 0.f);
                    u16 vh = bfhi(v), vl = bfhi(v - bf2f(vh));
                    scr[wrow + lg * 4 + rg][lr] = (u32)vh | ((u32)vl << 16);
                }
            }
            if (lg >= 2) {
                *(uint4*)&w[0] = *(const uint4*)&scr[wrow + lr][(lg - 2) * 8];
                *(uint4*)&w[4] = *(const uint4*)&scr[wrow + lr][(lg - 2) * 8 + 4];
            }
            bf8 a2H, a2L;
#pragma unroll
            for (int j = 0; j < 8; ++j) {
                ((u16*)&a2H)[j] = (u16)(w[j] & 0xffffu);
                ((u16*)&a2L)[j] = (u16)(w[j] >> 16);
            }
#pragma unroll
            for (int ct = 0; ct < 8; ++ct) {
                bf8 bH = *(const bf8*)&wbH[8 + kt * 8 + ct][l * 8];
                bf8 bL = *(const bf8*)&wbL[8 + kt * 8 + ct][l * 8];
                acc2[ct] = __builtin_amdgcn_mfma_f32_16x16x32_bf16(a2H, bH, acc2[ct], 0, 0, 0);
                acc2[ct] = __builtin_amdgcn_mfma_f32_16x16x32_bf16(a2L, bH, acc2[ct], 0, 0, 0);
                acc2[ct] = __builtin_amdgcn_mfma_f32_16x16x32_bf16(a2H, bL, acc2[ct], 0, 0, 0);
            }
        }

        // ---- stage 3: dec = relu(h2+bd2) @ Wd3 (tiles 40..71) ----
        f4 acc3[8];
#pragma unroll
        for (int ct = 0; ct < 8; ++ct) acc3[ct] = (f4){0.f, 0.f, 0.f, 0.f};
#pragma unroll
        for (int kt = 0; kt < 4; ++kt) {
            u32 w[8];
            {
                int ct = kt * 2;
                float bv = bd2[ct * 16 + lr];
#pragma unroll
                for (int rg = 0; rg < 4; ++rg) {
                    float v = fmaxf(acc2[ct][rg] + bv, 0.f);
                    u16 vh = bfhi(v), vl = bfhi(v - bf2f(vh));
                    scr[wrow + lg * 4 + rg][lr] = (u32)vh | ((u32)vl << 16);
                }
            }
            if (lg < 2) {
                *(uint4*)&w[0] = *(const uint4*)&scr[wrow + lr][lg * 8];
                *(uint4*)&w[4] = *(const uint4*)&scr[wrow + lr][lg * 8 + 4];
            }
            {
                int ct = kt * 2 + 1;
                float bv = bd2[ct * 16 + lr];
#pragma unroll
                for (int rg = 0; rg < 4; ++rg) {
                    float v = fmaxf(acc2[ct][rg] + bv, 0.f);
                    u16 vh = bfhi(v), vl = bfhi(v - bf2f(vh));
                    scr[wrow + lg * 4 + rg][lr] = (u32)vh | ((u32)vl << 16);
                }
            }
            if (lg >= 2) {
                *(uint4*)&w[0] = *(const uint4*)&scr[wrow + lr][(lg - 2) * 8];
                *(uint4*)&w[4] = *(const uint4*)&scr[wrow + lr][(lg - 2) * 8 + 4];
            }
            bf8 a3H, a3L;
#pragma unroll
            for (int j = 0; j < 8; ++j) {
                ((u16*)&a3H)[j] = (u16)(w[j] & 0xffffu);
                ((u16*)&a3L)[j] = (u16)(w[j] >> 16);
            }
#pragma unroll
            for (int ct = 0; ct < 8; ++ct) {
                bf8 bH = *(const bf8*)&wbH[40 + kt * 8 + ct][l * 8];
                bf8 bL = *(const bf8*)&wbL[40 + kt * 8 + ct][l * 8];
                acc3[ct] = __builtin_amdgcn_mfma_f32_16x16x32_bf16(a3H, bH, acc3[ct], 0, 0, 0);
                acc3[ct] = __builtin_amdgcn_mfma_f32_16x16x32_bf16(a3L, bH, acc3[ct], 0, 0, 0);
                acc3[ct] = __builtin_amdgcn_mfma_f32_16x16x32_bf16(a3H, bL, acc3[ct], 0, 0, 0);
            }
        }

        // ---- epilogue: softplus -> out[:,42:170) ----
#pragma unroll
        for (int ct = 0; ct < 8; ++ct) {
            float bv = bd3[ct * 16 + lr];
#pragma unroll
            for (int rg = 0; rg < 4; ++rg) {
                int g = row0 + wrow + lg * 4 + rg;
                if (g < n) {
                    float v = acc3[ct][rg] + bv;
                    v = fmaxf(v, 0.f) + __logf(1.f + __expf(-fabsf(v)));
                    out[(size_t)g * 170 + 42 + ct * 16 + lr] = v;
                }
            }
        }
    }
}

// ---------------- launch ----------------

extern "C" void kernel_launch(void* const* d_in, const int* in_sizes, int n_in,
                              void* d_out, int out_size, void* d_ws, size_t ws_size,
                              hipStream_t stream) {
    const float* raw_x = (const float*)d_in[0];
    const int*   ei    = (const int*)d_in[1];
    const float* W1 = (const float*)d_in[2];  const float* b1 = (const float*)d_in[3];
    const float* W2 = (const float*)d_in[4];  const float* b2 = (const float*)d_in[5];
    const float* Wp = (const float*)d_in[6];  const float* bp = (const float*)d_in[7];
    const float* Wd1 = (const float*)d_in[8]; const float* bd1 = (const float*)d_in[9];
    const float* Wd2 = (const float*)d_in[10]; const float* bd2 = (const float*)d_in[11];
    const float* Wd3 = (const float*)d_in[12]; const float* bd3 = (const float*)d_in[13];

    const int n = in_sizes[0] / 128;   // 50000
    const int E = in_sizes[1] / 2;     // 800000
    const int* row = ei;        // source
    const int* col = ei + E;    // target

    float* out = (float*)d_out;

    const int CH   = 8192;
    const int nwg  = (E + CH - 1) / CH;     // 98
    const int nbuk = (n + 63) >> 6;         // 782

    // workspace layout (aligned)
    char* ws = (char*)d_ws;
    auto alloc = [&](size_t bytes) {
        ws = (char*)(((uintptr_t)ws + 255) & ~(uintptr_t)255);
        char* p = ws; ws += bytes; return (void*)p;
    };
    float* dinv   = (float*)alloc((size_t)n * 4);
    int*   rowptr = (int*)alloc((size_t)(n + 4) * 4);
    int*   boff   = (int*)alloc((size_t)(nbuk + 4) * 4);
    int*   bsum   = (int*)alloc((size_t)nbuk * 4);
    int*   M      = (int*)alloc((size_t)nbuk * nwg * 4);
    int*   csrc   = (int*)alloc((size_t)E * 4);
    float* hs1    = (float*)alloc((size_t)n * 64 * 4);   // overlays ebuf (build)
    float* x1     = (float*)alloc((size_t)n * 64 * 4);
    float* hs2    = (float*)alloc((size_t)n * 32 * 4);
    u16*   wswHi  = (u16*)alloc((size_t)73 * 512 * 2);
    u16*   wswLo  = (u16*)alloc((size_t)73 * 512 * 2);
    int2*  ebuf   = (int2*)hs1;           // dead before gemm1 writes hs1

    const int BS = 256;
    auto blocks = [](long long work, int bs) { return (unsigned)((work + bs - 1) / bs); };
    const int ntiles = (n + 127) / 128;              // 391 (128-row decoder tiles)

    // ---- graph structure: bucketed counting sort (zero global atomics) ----
    bucket_hist<<<nwg, 256, 0, stream>>>(col, M, E, nbuk, nwg);
    col_scan<<<blocks(nbuk, 256), 256, 0, stream>>>(M, bsum, nbuk, nwg);
    bucket_scan<<<1, 1024, 0, stream>>>(bsum, boff, rowptr, nbuk, n, E);
    bucket_scatter<<<nwg, 256, 0, stream>>>(row, col, M, boff, ebuf, E, nwg);
    bucket_finalize<<<nbuk, 256, 0, stream>>>(ebuf, boff, rowptr, csrc, dinv, n);

    // ---- weight swizzle (independent) ----
    wswz_kernel<<<73, 64, 0, stream>>>(Wd1, Wd2, Wd3, Wp, wswHi, wswLo);

    // ---- GCN layer 1: raw_x[128] -> 64 ----
    gemm_gcn<128, 64><<<blocks(n, 64), 256, 0, stream>>>(raw_x, W1, dinv, hs1, n);
    agg_finalize<64, true><<<blocks((long long)n * 16, BS), BS, 0, stream>>>(
        rowptr, csrc, hs1, dinv, b1, x1, n, 64, 0);

    // ---- GCN layer 2: x1[64] -> 32 ----
    gemm_gcn<64, 32><<<blocks(n, 64), 256, 0, stream>>>(x1, W2, dinv, hs2, n);
    agg_finalize<32, false><<<blocks((long long)n * 8, BS), BS, 0, stream>>>(
        rowptr, csrc, hs2, dinv, b2, out, n, 170, 0);   // emb -> out[:,0:32)

    // ---- fully-fused decoder: 8 waves/block, weights resident in LDS ----
    dec_fused<<<256, 512, 0, stream>>>(out, wswHi, wswLo, bp, bd1, bd2, bd3, out, n, ntiles);
}